// Round 5
// baseline (234.001 us; speedup 1.0000x reference)
//
#include <hip/hip_runtime.h>
#include <cstdint>
#include <cstddef>

typedef unsigned short u16;
typedef unsigned char u8;
typedef __attribute__((ext_vector_type(8))) u16 u16x8;
typedef __attribute__((ext_vector_type(8))) __bf16 bf16x8;
typedef __attribute__((ext_vector_type(4))) float f32x4;
typedef __attribute__((ext_vector_type(16))) float f32x16;
typedef __attribute__((ext_vector_type(4))) int i32x4;
typedef __attribute__((ext_vector_type(8))) int i32x8;
typedef __attribute__((ext_vector_type(2))) int i32x2;

__device__ __forceinline__ u16 f2bf(float f) {
  unsigned u = __builtin_bit_cast(unsigned, f);
  return (u16)((u + 0x7FFFu + ((u >> 16) & 1u)) >> 16);
}
__device__ __forceinline__ float bf2f(u16 h) {
  return __builtin_bit_cast(float, (unsigned)h << 16);
}
__device__ __forceinline__ u8 f2fp8(float f) {
  return (u8)(__builtin_amdgcn_cvt_pk_fp8_f32(f, 0.f, 0, false) & 0xFF);
}
__device__ __forceinline__ f32x16 mfma32(u16x8 a, u16x8 b, f32x16 c) {
  return __builtin_amdgcn_mfma_f32_32x32x16_bf16(
      __builtin_bit_cast(bf16x8, a), __builtin_bit_cast(bf16x8, b), c, 0, 0, 0);
}
__device__ __forceinline__ unsigned cvtpk_bf16(float lo, float hi) {
  unsigned r;
  asm("v_cvt_pk_bf16_f32 %0, %1, %2" : "=v"(r) : "v"(lo), "v"(hi));
  return r;
}
__device__ __forceinline__ float exp2_fast(float x) {
  float r;
  asm("v_exp_f32 %0, %1" : "=v"(r) : "v"(x));
  return r;
}
__device__ __forceinline__ void plswap(unsigned& a, unsigned& b) {
  i32x2 r = __builtin_amdgcn_permlane32_swap((int)a, (int)b, false, false);
  a = (unsigned)r[0];
  b = (unsigned)r[1];
}
__device__ __forceinline__ void load_lds16(const void* g, void* l) {
  __builtin_amdgcn_global_load_lds(
      (const __attribute__((address_space(1))) void*)g,
      (__attribute__((address_space(3))) void*)l, 16, 0, 0);
}

// ---------------- fused pre-pass: 4 weight transposes (fp8) + x LayerNorm (fp8)
__global__ __launch_bounds__(256) void k_pre(
    const float* __restrict__ W1, const float* __restrict__ projW,
    const float* __restrict__ mlpW, const float* __restrict__ W2,
    u8* __restrict__ W1t, u8* __restrict__ pWt, u8* __restrict__ mWt,
    u8* __restrict__ W2t, const float* __restrict__ x,
    const float* __restrict__ g, const float* __restrict__ b,
    u8* __restrict__ nx8) {
  __shared__ float t[32][33];
  __shared__ float red[8];
  const int L = blockIdx.x;
  const int tid = threadIdx.x;
  if (L < 7680) {
    const float* src;
    u8* dst;
    int R, C, dR, dC, bx, by;
    if (L < 3840) {
      src = W1; dst = W1t; R = 1024; C = 3788; dR = 1024; dC = 3840;
      bx = L % 120; by = L / 120;
    } else if (L < 4864) {
      int tq = L - 3840;
      src = projW; dst = pWt; R = 1024; C = 1024; dR = 1024; dC = 1024;
      bx = tq & 31; by = tq >> 5;
    } else if (L < 5632) {
      int tq = L - 4864;
      src = mlpW; dst = mWt; R = 716; C = 1024; dR = 768; dC = 1024;
      bx = tq & 31; by = tq >> 5;
    } else {
      int tq = L - 5632;
      src = W2; dst = W2t; R = 2048; C = 1024; dR = 2048; dC = 1024;
      bx = tq & 31; by = tq >> 5;
    }
    const int n0 = bx * 32, k0 = by * 32;
    const int tx = tid & 31, ty = tid >> 5;
#pragma unroll
    for (int j = 0; j < 4; ++j) {
      int kk = k0 + ty + 8 * j, nn = n0 + tx;
      float v = (kk < R && nn < C) ? src[(size_t)kk * C + nn] : 0.f;
      t[ty + 8 * j][tx] = v;
    }
    __syncthreads();
#pragma unroll
    for (int j = 0; j < 4; ++j) {
      int nn = n0 + ty + 8 * j, kk = k0 + tx;
      if (nn < dC && kk < dR) dst[(size_t)nn * dR + kk] = f2fp8(t[tx][ty + 8 * j]);
    }
  } else {
    const int row = L - 7680;
    float4 v = ((const float4*)(x + (size_t)row * 1024))[tid];
    float s = v.x + v.y + v.z + v.w;
    float ss = v.x * v.x + v.y * v.y + v.z * v.z + v.w * v.w;
#pragma unroll
    for (int off = 1; off < 64; off <<= 1) {
      s += __shfl_xor(s, off);
      ss += __shfl_xor(ss, off);
    }
    const int wid = tid >> 6, lane = tid & 63;
    if (lane == 0) { red[wid] = s; red[4 + wid] = ss; }
    __syncthreads();
    s = red[0] + red[1] + red[2] + red[3];
    ss = red[4] + red[5] + red[6] + red[7];
    const float mean = s * (1.f / 1024.f);
    const float var = ss * (1.f / 1024.f) - mean * mean;
    const float rstd = rsqrtf(var + 1e-5f);
    float4 gv = ((const float4*)g)[tid];
    float4 bv = ((const float4*)b)[tid];
    float y0 = (v.x - mean) * rstd * gv.x + bv.x;
    float y1 = (v.y - mean) * rstd * gv.y + bv.y;
    float y2 = (v.z - mean) * rstd * gv.z + bv.z;
    float y3 = (v.w - mean) * rstd * gv.w + bv.w;
    int pk = __builtin_amdgcn_cvt_pk_fp8_f32(y0, y1, 0, false);
    pk = __builtin_amdgcn_cvt_pk_fp8_f32(y2, y3, pk, true);
    ((int*)(nx8 + (size_t)row * 1024))[tid] = pk;
  }
}

// ---------------- MX-fp8 GEMM core 128x128, 3-deep pipeline, counted vmcnt (T4)
__device__ __forceinline__ void gemm_fp8_core(const u8* __restrict__ A,
                                              const u8* __restrict__ B, int K,
                                              u8* Alds, u8* Blds,
                                              f32x16 (&acc)[2][2], int tid) {
  const int lane = tid & 63, wave = tid >> 6;
  const int h = lane >> 5, r32 = lane & 31;
  const int wrow = (wave >> 1) * 64, wcol = (wave & 1) * 64;
  const int srow0 = tid >> 2, spos = tid & 3;
  const int nk = K >> 6;
  auto STAGE = [&](int t, int bb) {
#pragma unroll
    for (int p = 0; p < 2; ++p) {
      const int row = p * 64 + srow0;
      const int c = spos ^ ((row >> 1) & 3);
      const size_t go = (size_t)row * K + (size_t)t * 64 + c * 16;
      load_lds16(A + go, Alds + bb * 8192 + (p * 256 + tid) * 16);
      load_lds16(B + go, Blds + bb * 8192 + (p * 256 + tid) * 16);
    }
  };
  STAGE(0, 0);
  STAGE(1, 1);
  asm volatile("s_waitcnt vmcnt(4)" ::: "memory");
  __builtin_amdgcn_s_barrier();
  int cur = 0;
  for (int kt = 0; kt < nk; ++kt) {
    const u8* Ac = Alds + cur * 8192;
    const u8* Bc = Blds + cur * 8192;
    i32x8 af[2], bf[2];
#pragma unroll
    for (int t = 0; t < 2; ++t) {
      {
        const int row = wrow + t * 32 + r32;
        const int sw = (row >> 1) & 3;
        i32x4 lo = *(const i32x4*)(Ac + row * 64 + ((2 * h) ^ sw) * 16);
        i32x4 hi = *(const i32x4*)(Ac + row * 64 + ((2 * h + 1) ^ sw) * 16);
        i32x8 a;
        a[0] = lo[0]; a[1] = lo[1]; a[2] = lo[2]; a[3] = lo[3];
        a[4] = hi[0]; a[5] = hi[1]; a[6] = hi[2]; a[7] = hi[3];
        af[t] = a;
      }
      {
        const int row = wcol + t * 32 + r32;
        const int sw = (row >> 1) & 3;
        i32x4 lo = *(const i32x4*)(Bc + row * 64 + ((2 * h) ^ sw) * 16);
        i32x4 hi = *(const i32x4*)(Bc + row * 64 + ((2 * h + 1) ^ sw) * 16);
        i32x8 b8;
        b8[0] = lo[0]; b8[1] = lo[1]; b8[2] = lo[2]; b8[3] = lo[3];
        b8[4] = hi[0]; b8[5] = hi[1]; b8[6] = hi[2]; b8[7] = hi[3];
        bf[t] = b8;
      }
    }
    if (kt + 2 < nk) STAGE(kt + 2, cur == 0 ? 2 : cur - 1);
#pragma unroll
    for (int i = 0; i < 2; ++i)
#pragma unroll
      for (int j = 0; j < 2; ++j)
        acc[i][j] = __builtin_amdgcn_mfma_scale_f32_32x32x64_f8f6f4(
            af[i], bf[j], acc[i][j], 0, 0, 0, 0x7F7F7F7F, 0, 0x7F7F7F7F);
    if (kt + 1 < nk) {
      if (kt + 2 < nk)
        asm volatile("s_waitcnt vmcnt(4)" ::: "memory");
      else
        asm volatile("s_waitcnt vmcnt(0)" ::: "memory");
      __builtin_amdgcn_s_barrier();
    }
    cur = (cur == 2) ? 0 : cur + 1;
  }
}

// ---------------- MX-fp8 GEMM core 64(M)x128(N), 3-deep pipeline, counted vmcnt
__device__ __forceinline__ void gemm_fp8_core64(const u8* __restrict__ A,
                                                const u8* __restrict__ B, int K,
                                                u8* Alds, u8* Blds,
                                                f32x16 (&acc)[2], int tid) {
  const int lane = tid & 63, wave = tid >> 6;
  const int h = lane >> 5, r32 = lane & 31;
  const int wrow = (wave >> 1) * 32, wcol = (wave & 1) * 64;
  const int nk = K >> 6;
  const int ra = tid >> 2, posa = tid & 3;
  const int ca = posa ^ ((ra >> 1) & 3);
  auto STAGE = [&](int t, int bb) {
    const size_t k0 = (size_t)t * 64;
    load_lds16(A + (size_t)ra * K + k0 + ca * 16, Alds + bb * 4096 + tid * 16);
#pragma unroll
    for (int p = 0; p < 2; ++p) {
      const int s = tid + 256 * p;
      const int r = s >> 2, pos = s & 3;
      const int c = pos ^ ((r >> 1) & 3);
      load_lds16(B + (size_t)r * K + k0 + c * 16, Blds + bb * 8192 + s * 16);
    }
  };
  STAGE(0, 0);
  STAGE(1, 1);
  asm volatile("s_waitcnt vmcnt(3)" ::: "memory");
  __builtin_amdgcn_s_barrier();
  int cur = 0;
  for (int kt = 0; kt < nk; ++kt) {
    const u8* Ac = Alds + cur * 4096;
    const u8* Bc = Blds + cur * 8192;
    i32x8 af, bf[2];
    {
      const int row = wrow + r32;
      const int sw = (row >> 1) & 3;
      i32x4 lo = *(const i32x4*)(Ac + row * 64 + ((2 * h) ^ sw) * 16);
      i32x4 hi = *(const i32x4*)(Ac + row * 64 + ((2 * h + 1) ^ sw) * 16);
      af[0] = lo[0]; af[1] = lo[1]; af[2] = lo[2]; af[3] = lo[3];
      af[4] = hi[0]; af[5] = hi[1]; af[6] = hi[2]; af[7] = hi[3];
    }
#pragma unroll
    for (int t = 0; t < 2; ++t) {
      const int row = wcol + t * 32 + r32;
      const int sw = (row >> 1) & 3;
      i32x4 lo = *(const i32x4*)(Bc + row * 64 + ((2 * h) ^ sw) * 16);
      i32x4 hi = *(const i32x4*)(Bc + row * 64 + ((2 * h + 1) ^ sw) * 16);
      i32x8 b8;
      b8[0] = lo[0]; b8[1] = lo[1]; b8[2] = lo[2]; b8[3] = lo[3];
      b8[4] = hi[0]; b8[5] = hi[1]; b8[6] = hi[2]; b8[7] = hi[3];
      bf[t] = b8;
    }
    if (kt + 2 < nk) STAGE(kt + 2, cur == 0 ? 2 : cur - 1);
#pragma unroll
    for (int j = 0; j < 2; ++j)
      acc[j] = __builtin_amdgcn_mfma_scale_f32_32x32x64_f8f6f4(
          af, bf[j], acc[j], 0, 0, 0, 0x7F7F7F7F, 0, 0x7F7F7F7F);
    if (kt + 1 < nk) {
      if (kt + 2 < nk)
        asm volatile("s_waitcnt vmcnt(3)" ::: "memory");
      else
        asm volatile("s_waitcnt vmcnt(0)" ::: "memory");
      __builtin_amdgcn_s_barrier();
    }
    cur = (cur == 2) ? 0 : cur + 1;
  }
}

// ---------------- GEMM1: f1[4096][3840] bf16 = nx8 @ W1t^T + b1
__global__ __launch_bounds__(256) void k_gemm1(const u8* __restrict__ nx8,
                                               const u8* __restrict__ W1t,
                                               u16* __restrict__ f1,
                                               const float* __restrict__ b1) {
  __shared__ __align__(16) u8 Alds[3 * 128 * 64];
  __shared__ __align__(16) u8 Blds[3 * 128 * 64];
  const int tid = threadIdx.x, bm = blockIdx.y, bn = blockIdx.x;
  f32x16 acc[2][2];
#pragma unroll
  for (int i = 0; i < 2; ++i)
#pragma unroll
    for (int j = 0; j < 2; ++j)
#pragma unroll
      for (int r = 0; r < 16; ++r) acc[i][j][r] = 0.f;
  gemm_fp8_core(nx8 + (size_t)bm * 128 * 1024, W1t + (size_t)bn * 128 * 1024, 1024,
                Alds, Blds, acc, tid);
  const int lane = tid & 63, wave = tid >> 6;
  const int h = lane >> 5, r32 = lane & 31;
  const int wrow = (wave >> 1) * 64, wcol = (wave & 1) * 64;
#pragma unroll
  for (int i = 0; i < 2; ++i)
#pragma unroll
    for (int j = 0; j < 2; ++j) {
      const int col = bn * 128 + wcol + j * 32 + r32;
      const float bs = (col < 3788) ? b1[col] : 0.f;
#pragma unroll
      for (int r = 0; r < 16; ++r) {
        const int row = bm * 128 + wrow + i * 32 + 4 * h + (r & 3) + 8 * (r >> 2);
        f1[(size_t)row * 3840 + col] = f2bf(acc[i][j][r] + bs);
      }
    }
}

// ---------------- proj + mlp fused (64-row tiles): comb[4096][2048] fp8
__global__ __launch_bounds__(256) void k_gemm_pm(
    const u8* __restrict__ xo, const u8* __restrict__ pWt,
    const u8* __restrict__ gel, const u8* __restrict__ mWt,
    u8* __restrict__ comb, const float* __restrict__ projb) {
  __shared__ __align__(16) u8 Alds[3 * 64 * 64];
  __shared__ __align__(16) u8 Blds[3 * 128 * 64];
  const int tid = threadIdx.x, bm = blockIdx.y, bnq = blockIdx.x;
  const u8* A;
  const u8* B;
  int K, colbase;
  const float* bias;
  if (bnq < 8) {
    A = xo + (size_t)bm * 64 * 1024;
    B = pWt + (size_t)bnq * 128 * 1024;
    K = 1024; colbase = bnq * 128; bias = projb;
  } else {
    A = gel + (size_t)bm * 64 * 768;
    B = mWt + (size_t)(bnq - 8) * 128 * 768;
    K = 768; colbase = 1024 + (bnq - 8) * 128; bias = nullptr;
  }
  f32x16 acc[2];
#pragma unroll
  for (int j = 0; j < 2; ++j)
#pragma unroll
    for (int r = 0; r < 16; ++r) acc[j][r] = 0.f;
  gemm_fp8_core64(A, B, K, Alds, Blds, acc, tid);
  const int lane = tid & 63, wave = tid >> 6;
  const int h = lane >> 5, r32 = lane & 31;
  const int wrow = (wave >> 1) * 32, wcol = (wave & 1) * 64;
#pragma unroll
  for (int j = 0; j < 2; ++j) {
    const int col = colbase + wcol + j * 32 + r32;
    const float bs = (bias != nullptr) ? bias[col] : 0.f;
#pragma unroll
    for (int r = 0; r < 16; ++r) {
      const int row = bm * 64 + wrow + 4 * h + (r & 3) + 8 * (r >> 2);
      comb[(size_t)row * 2048 + col] = f2fp8(acc[j][r] + bs);
    }
  }
}

// ---------------- final (64-row tiles): out = x + (comb @ W2t^T + b2) * ls_g
__global__ __launch_bounds__(256) void k_gemm_fin(const u8* __restrict__ comb,
                                                  const u8* __restrict__ W2t,
                                                  float* __restrict__ out,
                                                  const float* __restrict__ b2,
                                                  const float* __restrict__ x,
                                                  const float* __restrict__ lsg) {
  __shared__ __align__(16) u8 Alds[3 * 64 * 64];
  __shared__ __align__(16) u8 Blds[3 * 128 * 64];
  const int tid = threadIdx.x, bm = blockIdx.y, bn = blockIdx.x;
  f32x16 acc[2];
#pragma unroll
  for (int j = 0; j < 2; ++j)
#pragma unroll
    for (int r = 0; r < 16; ++r) acc[j][r] = 0.f;
  gemm_fp8_core64(comb + (size_t)bm * 64 * 2048, W2t + (size_t)bn * 128 * 2048, 2048,
                  Alds, Blds, acc, tid);
  const int lane = tid & 63, wave = tid >> 6;
  const int h = lane >> 5, r32 = lane & 31;
  const int wrow = (wave >> 1) * 32, wcol = (wave & 1) * 64;
#pragma unroll
  for (int j = 0; j < 2; ++j) {
    const int col = bn * 128 + wcol + j * 32 + r32;
    const float bs = b2[col], ls = lsg[col];
#pragma unroll
    for (int r = 0; r < 16; ++r) {
      const int row = bm * 64 + wrow + 4 * h + (r & 3) + 8 * (r >> 2);
      out[(size_t)row * 1024 + col] =
          x[(size_t)row * 1024 + col] + (acc[j][r] + bs) * ls;
    }
  }
}

// ---------------- fused mid-pass: q/k per-head LN + gelu, plus V^T extraction.
__global__ __launch_bounds__(256) void k_mid(const u16* __restrict__ f1,
                                             const float* __restrict__ qg,
                                             const float* __restrict__ qbb,
                                             const float* __restrict__ kg,
                                             const float* __restrict__ kbb,
                                             u16* __restrict__ q,
                                             u16* __restrict__ k,
                                             u8* __restrict__ gel,
                                             u16* __restrict__ vtb) {
  __shared__ u16 tt[32][33];
  const int tid = threadIdx.x;
  const int L = blockIdx.x;
  if (L < 4096) {
    const int row = L;
    const int rem = tid >> 3;
    const int which = rem >> 4, h = rem & 15;
    const int e8 = (tid & 7) * 8;
    u16x8 xv = *(const u16x8*)(f1 + (size_t)row * 3840 + which * 1024 + h * 64 + e8);
    float xf[8];
    float s1 = 0.f, s2 = 0.f;
#pragma unroll
    for (int e = 0; e < 8; ++e) {
      xf[e] = bf2f(xv[e]);
      s1 += xf[e];
      s2 += xf[e] * xf[e];
    }
#pragma unroll
    for (int off = 1; off < 8; off <<= 1) {
      s1 += __shfl_xor(s1, off);
      s2 += __shfl_xor(s2, off);
    }
    const float mean = s1 * (1.f / 64.f);
    const float var = s2 * (1.f / 64.f) - mean * mean;
    const float rstd = rsqrtf(var + 1e-5f);
    const float* g = (which == 0) ? qg : kg;
    const float* bb = (which == 0) ? qbb : kbb;
    float4 g0 = ((const float4*)g)[e8 >> 2], g1 = ((const float4*)g)[(e8 >> 2) + 1];
    float4 b0 = ((const float4*)bb)[e8 >> 2], b1 = ((const float4*)bb)[(e8 >> 2) + 1];
    float gv[8] = {g0.x, g0.y, g0.z, g0.w, g1.x, g1.y, g1.z, g1.w};
    float bv[8] = {b0.x, b0.y, b0.z, b0.w, b1.x, b1.y, b1.z, b1.w};
    u16x8 o;
#pragma unroll
    for (int e = 0; e < 8; ++e) o[e] = f2bf((xf[e] - mean) * rstd * gv[e] + bv[e]);
    const int b = row >> 10, n = row & 1023;
    u16* dst = (which == 0) ? q : k;
    *(u16x8*)(dst + ((size_t)(b * 16 + h) * 1024 + n) * 64 + e8) = o;
  } else if (L < 5632) {
    const int id = (L - 4096) * 256 + tid;
    const int row = id / 96, c8 = id - row * 96;
    u16x8 xv = *(const u16x8*)(f1 + (size_t)row * 3840 + 3072 + c8 * 8);
    float rr[8];
#pragma unroll
    for (int e = 0; e < 8; ++e) {
      const int col = c8 * 8 + e;
      rr[e] = 0.f;
      if (col < 716) {
        float xx = bf2f(xv[e]);
        rr[e] = 0.5f * xx * (1.f + erff(xx * 0.70710678118654752f));
      }
    }
    int p0 = __builtin_amdgcn_cvt_pk_fp8_f32(rr[0], rr[1], 0, false);
    p0 = __builtin_amdgcn_cvt_pk_fp8_f32(rr[2], rr[3], p0, true);
    int p1 = __builtin_amdgcn_cvt_pk_fp8_f32(rr[4], rr[5], 0, false);
    p1 = __builtin_amdgcn_cvt_pk_fp8_f32(rr[6], rr[7], p1, true);
    uint2 pk;
    pk.x = (unsigned)p0;
    pk.y = (unsigned)p1;
    *(uint2*)(gel + (size_t)row * 768 + c8 * 8) = pk;
  } else {
    const int t = L - 5632;
    const int xq = t & 1, yq = (t >> 1) & 31, z = t >> 6;
    const int b = z >> 4, h = z & 15;
    const int d0 = xq * 32, n0 = yq * 32;
    const int tx = tid & 31, ty = tid >> 5;
#pragma unroll
    for (int j = 0; j < 4; ++j)
      tt[ty + 8 * j][tx] =
          f1[(size_t)(b * 1024 + n0 + ty + 8 * j) * 3840 + 2048 + h * 64 + d0 + tx];
    __syncthreads();
#pragma unroll
    for (int j = 0; j < 4; ++j)
      vtb[(size_t)z * 65536 + (size_t)(d0 + ty + 8 * j) * 1024 + n0 + tx] =
          tt[tx][ty + 8 * j];
  }
}

// ---------------- flash attention v5: 1 wave per block, 32 q-rows, KVBLK=32,
// grid 2048. ZERO barriers: wave-local counted vmcnt(8) (T4) for double-buffered
// K/V staging; fragment-first schedule (read all tile frags -> lgkmcnt(0) ->
// STAGE(t+2) into vacated buffer -> compute). Swapped QK^T + in-register P
// (cvt_pk + permlane32_swap, T12). exp2-folded softmax. 16KB LDS, 8 blocks/CU
// fully async -> cross-wave MFMA/VALU overlap (no lockstep).
__global__ __launch_bounds__(64) void k_flash(const u16* __restrict__ q,
                                              const u16* __restrict__ k,
                                              const u16* __restrict__ vt,
                                              u8* __restrict__ xo) {
  __shared__ __align__(16) u16 Kl[2][32 * 64];
  __shared__ __align__(16) u16 Vl[2][64 * 32];
  const int lane = threadIdx.x & 63;
  const int l31 = lane & 31, h = lane >> 5;
  const int L = blockIdx.x;
  const int xcd = L & 7, i = L >> 3;          // i 0..255
  const int bh = xcd * 8 + (i & 7);           // 8 bh per XCD
  const int qt = i >> 3;                      // qt 0..31
  const int qrow0 = qt * 32;
  const u16* qb = q + ((size_t)bh * 1024 + qrow0) * 64;
  const u16* kb = k + (size_t)bh * 1024 * 64;
  const u16* vb = vt + (size_t)bh * 64 * 1024;

  // Q as B-frag: lane holds Q[q=l31][d = ds*16 + h*8 + e]
  u16x8 qf[4];
#pragma unroll
  for (int ds = 0; ds < 4; ++ds)
    qf[ds] = *(const u16x8*)(qb + (size_t)l31 * 64 + ds * 16 + h * 8);
  asm volatile("s_waitcnt vmcnt(0)" ::: "memory");  // Q in regs; vmcnt now clean

  f32x16 O[2];
#pragma unroll
  for (int d2 = 0; d2 < 2; ++d2)
#pragma unroll
    for (int r = 0; r < 16; ++r) O[d2][r] = 0.f;
  float lacc = 0.f;

  // staging: K tile [32 rows][128B], 8 granules/row, swzK(r) = (r^(r>>3))&7
  //          V tile [64 rows][64B],  4 granules/row, swzV(r) = (r>>1)&3
  auto STAGE = [&](int t, int bb) {
#pragma unroll
    for (int p = 0; p < 4; ++p) {
      const int s = lane + 64 * p;
      const int kr = s >> 3, kslot = s & 7;
      const int kc = kslot ^ ((kr ^ (kr >> 3)) & 7);
      load_lds16(kb + (size_t)(t * 32 + kr) * 64 + kc * 8, (u16*)Kl[bb] + s * 8);
      const int vr = s >> 2, vslot = s & 3;
      const int vc = vslot ^ ((vr >> 1) & 3);
      load_lds16(vb + (size_t)vr * 1024 + t * 32 + vc * 8, (u16*)Vl[bb] + s * 8);
    }
  };
  STAGE(0, 0);
  STAGE(1, 1);

  const int swzk = (l31 & 7) ^ ((l31 >> 3) & 3);  // swzK(l31)
  for (int t = 0; t < 32; ++t) {
    if (t < 31)
      asm volatile("s_waitcnt vmcnt(8)" ::: "memory");  // tile t landed
    else
      asm volatile("s_waitcnt vmcnt(0)" ::: "memory");
    const u16* Kc = (const u16*)Kl[t & 1];
    const u16* Vc = (const u16*)Vl[t & 1];
    // read all fragments of tile t into registers
    u16x8 kf[4], vf[4];
#pragma unroll
    for (int ds = 0; ds < 4; ++ds) {
      const int pos = (ds * 2 + h) ^ swzk;
      kf[ds] = *(const u16x8*)(Kc + l31 * 64 + pos * 8);
    }
#pragma unroll
    for (int m = 0; m < 2; ++m)
#pragma unroll
      for (int d2 = 0; d2 < 2; ++d2) {
        const int vr = d2 * 32 + l31;
        const int pos = (m * 2 + h) ^ ((vr >> 1) & 3);
        vf[m * 2 + d2] = *(const u16x8*)(Vc + vr * 32 + pos * 8);
      }
    asm volatile("s_waitcnt lgkmcnt(0)" ::: "memory");  // frags in regs
    if (t + 2 < 32) STAGE(t + 2, t & 1);                // reuse vacated buffer

    // S^T = K x Q^T : lane holds S[q=l31][16 keys (reg-mapped)]
    f32x16 S;
#pragma unroll
    for (int r = 0; r < 16; ++r) S[r] = 0.f;
    __builtin_amdgcn_s_setprio(1);
#pragma unroll
    for (int ds = 0; ds < 4; ++ds) S = mfma32(kf[ds], qf[ds], S);
    __builtin_amdgcn_s_setprio(0);

    // softmax (no-max; |s|<=8 after q/k LN): 2^(S * 0.125*log2e)
#pragma unroll
    for (int r = 0; r < 16; ++r) {
      float pv = exp2_fast(S[r] * 0.18033688011112042f);
      S[r] = pv;
      lacc += pv;
    }

    // PV: rebuild A-frag in-register (cvt_pk + permlane32_swap)
    __builtin_amdgcn_s_setprio(1);
#pragma unroll
    for (int m = 0; m < 2; ++m) {
      const int ro = m * 8;
      unsigned w0 = cvtpk_bf16(S[ro + 0], S[ro + 1]);
      unsigned w2 = cvtpk_bf16(S[ro + 4], S[ro + 5]);
      unsigned w1 = cvtpk_bf16(S[ro + 2], S[ro + 3]);
      unsigned w3 = cvtpk_bf16(S[ro + 6], S[ro + 7]);
      plswap(w0, w2);
      plswap(w1, w3);
      i32x4 aw;
      aw[0] = (int)w0; aw[1] = (int)w1; aw[2] = (int)w2; aw[3] = (int)w3;
      const u16x8 pa = __builtin_bit_cast(u16x8, aw);
#pragma unroll
      for (int d2 = 0; d2 < 2; ++d2) O[d2] = mfma32(pa, vf[m * 2 + d2], O[d2]);
    }
    __builtin_amdgcn_s_setprio(0);
  }

  // lane l and l^32 hold complementary key-subsets of the same q-row
  lacc += __shfl_xor(lacc, 32);
  const float inv = 1.f / lacc;
  const int b = bh >> 4, hh = bh & 15;
#pragma unroll
  for (int r = 0; r < 16; ++r) {
    const int qr = (r & 3) + 8 * (r >> 2) + 4 * h;
    const float invr = __shfl(inv, qr);
    u8* orow = xo + (size_t)(b * 1024 + qrow0 + qr) * 1024 + hh * 64;
    orow[l31] = f2fp8(O[0][r] * invr);
    orow[32 + l31] = f2fp8(O[1][r] * invr);
  }
}

extern "C" void kernel_launch(void* const* d_in, const int* in_sizes, int n_in,
                              void* d_out, int out_size, void* d_ws, size_t ws_size,
                              hipStream_t stream) {
  (void)in_sizes; (void)n_in; (void)out_size; (void)ws_size;
  const float* x      = (const float*)d_in[0];
  const float* norm_g = (const float*)d_in[1];
  const float* norm_b = (const float*)d_in[2];
  const float* W1     = (const float*)d_in[3];
  const float* b1     = (const float*)d_in[4];
  const float* qn_g   = (const float*)d_in[5];
  const float* qn_b   = (const float*)d_in[6];
  const float* kn_g   = (const float*)d_in[7];
  const float* kn_b   = (const float*)d_in[8];
  const float* projW  = (const float*)d_in[9];
  const float* projb  = (const float*)d_in[10];
  const float* mlpW   = (const float*)d_in[11];
  const float* W2     = (const float*)d_in[12];
  const float* b2     = (const float*)d_in[13];
  const float* ls_g   = (const float*)d_in[14];

  char* ws = (char*)d_ws;
  u8*  W1t8 = (u8*)(ws + 0);           // [3840][1024]  3,932,160
  u8*  pWt8 = (u8*)(ws + 3932160);     // [1024][1024]  1,048,576
  u8*  mWt8 = (u8*)(ws + 4980736);     // [1024][768]     786,432
  u8*  W2t8 = (u8*)(ws + 5767168);     // [1024][2048]  2,097,152
  u8*  nx8  = (u8*)(ws + 7864320);     // [4096][1024]  4,194,304 (then xo8)
  u16* f1   = (u16*)(ws + 12058624);   // [4096][3840] 31,457,280 bf16 (then comb fp8)
  u16* qbuf = (u16*)(ws + 43515904);   // [64][1024][64] 8,388,608
  u16* kbuf = (u16*)(ws + 51904512);   // [64][1024][64] 8,388,608
  u16* vtb  = (u16*)(ws + 60293120);   // [64][64][1024] 8,388,608
  u8*  gel8 = (u8*)(ws + 68681728);    // [4096][768]   3,145,728

  k_pre<<<11776, 256, 0, stream>>>(W1, projW, mlpW, W2, W1t8, pWt8, mWt8, W2t8,
                                   x, norm_g, norm_b, nx8);
  k_gemm1<<<dim3(30, 32), 256, 0, stream>>>(nx8, W1t8, f1, b1);
  k_mid<<<9728, 256, 0, stream>>>(f1, qn_g, qn_b, kn_g, kn_b, qbuf, kbuf, gel8,
                                  vtb);
  k_flash<<<2048, 64, 0, stream>>>(qbuf, kbuf, vtb, nx8);
  k_gemm_pm<<<dim3(16, 64), 256, 0, stream>>>(nx8, pWt8, gel8, mWt8, (u8*)f1, projb);
  k_gemm_fin<<<dim3(8, 64), 256, 0, stream>>>((u8*)f1, W2t8, (float*)d_out, b2, x,
                                              ls_g);
}

// Round 6
// 231.778 us; speedup vs baseline: 1.0096x; 1.0096x over previous
//
#include <hip/hip_runtime.h>
#include <cstdint>
#include <cstddef>

typedef unsigned short u16;
typedef unsigned char u8;
typedef __attribute__((ext_vector_type(8))) u16 u16x8;
typedef __attribute__((ext_vector_type(8))) __bf16 bf16x8;
typedef __attribute__((ext_vector_type(4))) float f32x4;
typedef __attribute__((ext_vector_type(16))) float f32x16;
typedef __attribute__((ext_vector_type(4))) int i32x4;
typedef __attribute__((ext_vector_type(8))) int i32x8;
typedef __attribute__((ext_vector_type(2))) int i32x2;

__device__ __forceinline__ u16 f2bf(float f) {
  unsigned u = __builtin_bit_cast(unsigned, f);
  return (u16)((u + 0x7FFFu + ((u >> 16) & 1u)) >> 16);
}
__device__ __forceinline__ float bf2f(u16 h) {
  return __builtin_bit_cast(float, (unsigned)h << 16);
}
__device__ __forceinline__ u8 f2fp8(float f) {
  return (u8)(__builtin_amdgcn_cvt_pk_fp8_f32(f, 0.f, 0, false) & 0xFF);
}
__device__ __forceinline__ f32x16 mfma32(u16x8 a, u16x8 b, f32x16 c) {
  return __builtin_amdgcn_mfma_f32_32x32x16_bf16(
      __builtin_bit_cast(bf16x8, a), __builtin_bit_cast(bf16x8, b), c, 0, 0, 0);
}
__device__ __forceinline__ unsigned cvtpk_bf16(float lo, float hi) {
  unsigned r;
  asm("v_cvt_pk_bf16_f32 %0, %1, %2" : "=v"(r) : "v"(lo), "v"(hi));
  return r;
}
__device__ __forceinline__ float exp2_fast(float x) {
  float r;
  asm("v_exp_f32 %0, %1" : "=v"(r) : "v"(x));
  return r;
}
__device__ __forceinline__ void plswap(unsigned& a, unsigned& b) {
  i32x2 r = __builtin_amdgcn_permlane32_swap((int)a, (int)b, false, false);
  a = (unsigned)r[0];
  b = (unsigned)r[1];
}
__device__ __forceinline__ void load_lds16(const void* g, void* l) {
  __builtin_amdgcn_global_load_lds(
      (const __attribute__((address_space(1))) void*)g,
      (__attribute__((address_space(3))) void*)l, 16, 0, 0);
}

// ---------------- fused pre-pass: 4 weight transposes (fp8) + x LayerNorm (fp8)
__global__ __launch_bounds__(256) void k_pre(
    const float* __restrict__ W1, const float* __restrict__ projW,
    const float* __restrict__ mlpW, const float* __restrict__ W2,
    u8* __restrict__ W1t, u8* __restrict__ pWt, u8* __restrict__ mWt,
    u8* __restrict__ W2t, const float* __restrict__ x,
    const float* __restrict__ g, const float* __restrict__ b,
    u8* __restrict__ nx8) {
  __shared__ float t[32][33];
  __shared__ float red[8];
  const int L = blockIdx.x;
  const int tid = threadIdx.x;
  if (L < 7680) {
    const float* src;
    u8* dst;
    int R, C, dR, dC, bx, by;
    if (L < 3840) {
      src = W1; dst = W1t; R = 1024; C = 3788; dR = 1024; dC = 3840;
      bx = L % 120; by = L / 120;
    } else if (L < 4864) {
      int tq = L - 3840;
      src = projW; dst = pWt; R = 1024; C = 1024; dR = 1024; dC = 1024;
      bx = tq & 31; by = tq >> 5;
    } else if (L < 5632) {
      int tq = L - 4864;
      src = mlpW; dst = mWt; R = 716; C = 1024; dR = 768; dC = 1024;
      bx = tq & 31; by = tq >> 5;
    } else {
      int tq = L - 5632;
      src = W2; dst = W2t; R = 2048; C = 1024; dR = 2048; dC = 1024;
      bx = tq & 31; by = tq >> 5;
    }
    const int n0 = bx * 32, k0 = by * 32;
    const int tx = tid & 31, ty = tid >> 5;
#pragma unroll
    for (int j = 0; j < 4; ++j) {
      int kk = k0 + ty + 8 * j, nn = n0 + tx;
      float v = (kk < R && nn < C) ? src[(size_t)kk * C + nn] : 0.f;
      t[ty + 8 * j][tx] = v;
    }
    __syncthreads();
#pragma unroll
    for (int j = 0; j < 4; ++j) {
      int nn = n0 + ty + 8 * j, kk = k0 + tx;
      if (nn < dC && kk < dR) dst[(size_t)nn * dR + kk] = f2fp8(t[tx][ty + 8 * j]);
    }
  } else {
    const int row = L - 7680;
    float4 v = ((const float4*)(x + (size_t)row * 1024))[tid];
    float s = v.x + v.y + v.z + v.w;
    float ss = v.x * v.x + v.y * v.y + v.z * v.z + v.w * v.w;
#pragma unroll
    for (int off = 1; off < 64; off <<= 1) {
      s += __shfl_xor(s, off);
      ss += __shfl_xor(ss, off);
    }
    const int wid = tid >> 6, lane = tid & 63;
    if (lane == 0) { red[wid] = s; red[4 + wid] = ss; }
    __syncthreads();
    s = red[0] + red[1] + red[2] + red[3];
    ss = red[4] + red[5] + red[6] + red[7];
    const float mean = s * (1.f / 1024.f);
    const float var = ss * (1.f / 1024.f) - mean * mean;
    const float rstd = rsqrtf(var + 1e-5f);
    float4 gv = ((const float4*)g)[tid];
    float4 bv = ((const float4*)b)[tid];
    float y0 = (v.x - mean) * rstd * gv.x + bv.x;
    float y1 = (v.y - mean) * rstd * gv.y + bv.y;
    float y2 = (v.z - mean) * rstd * gv.z + bv.z;
    float y3 = (v.w - mean) * rstd * gv.w + bv.w;
    int pk = __builtin_amdgcn_cvt_pk_fp8_f32(y0, y1, 0, false);
    pk = __builtin_amdgcn_cvt_pk_fp8_f32(y2, y3, pk, true);
    ((int*)(nx8 + (size_t)row * 1024))[tid] = pk;
  }
}

// ---------------- MX-fp8 GEMM core 128x128, 3-deep pipeline, counted vmcnt (T4)
__device__ __forceinline__ void gemm_fp8_core(const u8* __restrict__ A,
                                              const u8* __restrict__ B, int K,
                                              u8* Alds, u8* Blds,
                                              f32x16 (&acc)[2][2], int tid) {
  const int lane = tid & 63, wave = tid >> 6;
  const int h = lane >> 5, r32 = lane & 31;
  const int wrow = (wave >> 1) * 64, wcol = (wave & 1) * 64;
  const int srow0 = tid >> 2, spos = tid & 3;
  const int nk = K >> 6;
  auto STAGE = [&](int t, int bb) {
#pragma unroll
    for (int p = 0; p < 2; ++p) {
      const int row = p * 64 + srow0;
      const int c = spos ^ ((row >> 1) & 3);
      const size_t go = (size_t)row * K + (size_t)t * 64 + c * 16;
      load_lds16(A + go, Alds + bb * 8192 + (p * 256 + tid) * 16);
      load_lds16(B + go, Blds + bb * 8192 + (p * 256 + tid) * 16);
    }
  };
  STAGE(0, 0);
  STAGE(1, 1);
  asm volatile("s_waitcnt vmcnt(4)" ::: "memory");
  __builtin_amdgcn_s_barrier();
  int cur = 0;
  for (int kt = 0; kt < nk; ++kt) {
    const u8* Ac = Alds + cur * 8192;
    const u8* Bc = Blds + cur * 8192;
    i32x8 af[2], bf[2];
#pragma unroll
    for (int t = 0; t < 2; ++t) {
      {
        const int row = wrow + t * 32 + r32;
        const int sw = (row >> 1) & 3;
        i32x4 lo = *(const i32x4*)(Ac + row * 64 + ((2 * h) ^ sw) * 16);
        i32x4 hi = *(const i32x4*)(Ac + row * 64 + ((2 * h + 1) ^ sw) * 16);
        i32x8 a;
        a[0] = lo[0]; a[1] = lo[1]; a[2] = lo[2]; a[3] = lo[3];
        a[4] = hi[0]; a[5] = hi[1]; a[6] = hi[2]; a[7] = hi[3];
        af[t] = a;
      }
      {
        const int row = wcol + t * 32 + r32;
        const int sw = (row >> 1) & 3;
        i32x4 lo = *(const i32x4*)(Bc + row * 64 + ((2 * h) ^ sw) * 16);
        i32x4 hi = *(const i32x4*)(Bc + row * 64 + ((2 * h + 1) ^ sw) * 16);
        i32x8 b8;
        b8[0] = lo[0]; b8[1] = lo[1]; b8[2] = lo[2]; b8[3] = lo[3];
        b8[4] = hi[0]; b8[5] = hi[1]; b8[6] = hi[2]; b8[7] = hi[3];
        bf[t] = b8;
      }
    }
    if (kt + 2 < nk) STAGE(kt + 2, cur == 0 ? 2 : cur - 1);
#pragma unroll
    for (int i = 0; i < 2; ++i)
#pragma unroll
      for (int j = 0; j < 2; ++j)
        acc[i][j] = __builtin_amdgcn_mfma_scale_f32_32x32x64_f8f6f4(
            af[i], bf[j], acc[i][j], 0, 0, 0, 0x7F7F7F7F, 0, 0x7F7F7F7F);
    if (kt + 1 < nk) {
      if (kt + 2 < nk)
        asm volatile("s_waitcnt vmcnt(4)" ::: "memory");
      else
        asm volatile("s_waitcnt vmcnt(0)" ::: "memory");
      __builtin_amdgcn_s_barrier();
    }
    cur = (cur == 2) ? 0 : cur + 1;
  }
}

// ---------------- MX-fp8 GEMM core 64(M)x128(N), 3-deep pipeline, counted vmcnt
__device__ __forceinline__ void gemm_fp8_core64(const u8* __restrict__ A,
                                                const u8* __restrict__ B, int K,
                                                u8* Alds, u8* Blds,
                                                f32x16 (&acc)[2], int tid) {
  const int lane = tid & 63, wave = tid >> 6;
  const int h = lane >> 5, r32 = lane & 31;
  const int wrow = (wave >> 1) * 32, wcol = (wave & 1) * 64;
  const int nk = K >> 6;
  const int ra = tid >> 2, posa = tid & 3;
  const int ca = posa ^ ((ra >> 1) & 3);
  auto STAGE = [&](int t, int bb) {
    const size_t k0 = (size_t)t * 64;
    load_lds16(A + (size_t)ra * K + k0 + ca * 16, Alds + bb * 4096 + tid * 16);
#pragma unroll
    for (int p = 0; p < 2; ++p) {
      const int s = tid + 256 * p;
      const int r = s >> 2, pos = s & 3;
      const int c = pos ^ ((r >> 1) & 3);
      load_lds16(B + (size_t)r * K + k0 + c * 16, Blds + bb * 8192 + s * 16);
    }
  };
  STAGE(0, 0);
  STAGE(1, 1);
  asm volatile("s_waitcnt vmcnt(3)" ::: "memory");
  __builtin_amdgcn_s_barrier();
  int cur = 0;
  for (int kt = 0; kt < nk; ++kt) {
    const u8* Ac = Alds + cur * 4096;
    const u8* Bc = Blds + cur * 8192;
    i32x8 af, bf[2];
    {
      const int row = wrow + r32;
      const int sw = (row >> 1) & 3;
      i32x4 lo = *(const i32x4*)(Ac + row * 64 + ((2 * h) ^ sw) * 16);
      i32x4 hi = *(const i32x4*)(Ac + row * 64 + ((2 * h + 1) ^ sw) * 16);
      af[0] = lo[0]; af[1] = lo[1]; af[2] = lo[2]; af[3] = lo[3];
      af[4] = hi[0]; af[5] = hi[1]; af[6] = hi[2]; af[7] = hi[3];
    }
#pragma unroll
    for (int t = 0; t < 2; ++t) {
      const int row = wcol + t * 32 + r32;
      const int sw = (row >> 1) & 3;
      i32x4 lo = *(const i32x4*)(Bc + row * 64 + ((2 * h) ^ sw) * 16);
      i32x4 hi = *(const i32x4*)(Bc + row * 64 + ((2 * h + 1) ^ sw) * 16);
      i32x8 b8;
      b8[0] = lo[0]; b8[1] = lo[1]; b8[2] = lo[2]; b8[3] = lo[3];
      b8[4] = hi[0]; b8[5] = hi[1]; b8[6] = hi[2]; b8[7] = hi[3];
      bf[t] = b8;
    }
    if (kt + 2 < nk) STAGE(kt + 2, cur == 0 ? 2 : cur - 1);
#pragma unroll
    for (int j = 0; j < 2; ++j)
      acc[j] = __builtin_amdgcn_mfma_scale_f32_32x32x64_f8f6f4(
          af, bf[j], acc[j], 0, 0, 0, 0x7F7F7F7F, 0, 0x7F7F7F7F);
    if (kt + 1 < nk) {
      if (kt + 2 < nk)
        asm volatile("s_waitcnt vmcnt(3)" ::: "memory");
      else
        asm volatile("s_waitcnt vmcnt(0)" ::: "memory");
      __builtin_amdgcn_s_barrier();
    }
    cur = (cur == 2) ? 0 : cur + 1;
  }
}

// ---------------- GEMM1 + fused epilogue:
// bn<16  : q/k per-head LayerNorm (d=64 = one wave's 64-col tile) -> qbuf/kbuf bf16
// bn<24  : V region -> f1 bf16 (consumed by VT transpose)
// bn>=24 : mlp hidden -> gelu -> gel8 fp8
// LN/gelu run on full-f32 accumulator (more accurate than old bf16 round-trip).
__global__ __launch_bounds__(256) void k_gemm1(
    const u8* __restrict__ nx8, const u8* __restrict__ W1t, u16* __restrict__ f1,
    const float* __restrict__ b1, const float* __restrict__ qg,
    const float* __restrict__ qb_, const float* __restrict__ kg,
    const float* __restrict__ kb_, u16* __restrict__ qbuf, u16* __restrict__ kbuf,
    u8* __restrict__ gel8) {
  __shared__ __align__(16) u8 Alds[3 * 128 * 64];
  __shared__ __align__(16) u8 Blds[3 * 128 * 64];
  const int tid = threadIdx.x, bm = blockIdx.y, bn = blockIdx.x;
  f32x16 acc[2][2];
#pragma unroll
  for (int i = 0; i < 2; ++i)
#pragma unroll
    for (int j = 0; j < 2; ++j)
#pragma unroll
      for (int r = 0; r < 16; ++r) acc[i][j][r] = 0.f;
  gemm_fp8_core(nx8 + (size_t)bm * 128 * 1024, W1t + (size_t)bn * 128 * 1024, 1024,
                Alds, Blds, acc, tid);
  const int lane = tid & 63, wave = tid >> 6;
  const int h = lane >> 5, r32 = lane & 31;
  const int wrow = (wave >> 1) * 64, wcol = (wave & 1) * 64;
  if (bn < 16) {
    // q/k LN: wave owns one head's 64 d-cols for 64 rows.
    const int wc = bn * 128 + wcol;     // multiple of 64, < 2048
    const int which = wc >> 10;         // 0 = q, 1 = k
    const int head = (wc >> 6) & 15;
    const float* g = which ? kg : qg;
    const float* bb = which ? kb_ : qb_;
    const float g0 = g[r32], g1 = g[32 + r32];
    const float be0 = bb[r32], be1 = bb[32 + r32];
    const float bias0 = b1[wc + r32], bias1 = b1[wc + 32 + r32];
    u16* dst = which ? kbuf : qbuf;
#pragma unroll
    for (int i = 0; i < 2; ++i)
#pragma unroll
      for (int r = 0; r < 16; ++r) {
        float v0 = acc[i][0][r] + bias0;
        float v1 = acc[i][1][r] + bias1;
        float s = v0 + v1, ss = v0 * v0 + v1 * v1;
#pragma unroll
        for (int off = 1; off < 32; off <<= 1) {
          s += __shfl_xor(s, off);
          ss += __shfl_xor(ss, off);
        }
        const float mean = s * (1.f / 64.f);
        const float var = ss * (1.f / 64.f) - mean * mean;
        const float rstd = rsqrtf(var + 1e-5f);
        const int row = bm * 128 + wrow + i * 32 + 4 * h + (r & 3) + 8 * (r >> 2);
        const int b = row >> 10, n = row & 1023;
        u16* orow = dst + ((size_t)(b * 16 + head) * 1024 + n) * 64;
        orow[r32] = f2bf((v0 - mean) * rstd * g0 + be0);
        orow[32 + r32] = f2bf((v1 - mean) * rstd * g1 + be1);
      }
  } else if (bn < 24) {
    // V region -> f1 (cols 2048..3071)
#pragma unroll
    for (int i = 0; i < 2; ++i)
#pragma unroll
      for (int j = 0; j < 2; ++j) {
        const int col = bn * 128 + wcol + j * 32 + r32;
        const float bs = b1[col];
#pragma unroll
        for (int r = 0; r < 16; ++r) {
          const int row = bm * 128 + wrow + i * 32 + 4 * h + (r & 3) + 8 * (r >> 2);
          f1[(size_t)row * 3840 + col] = f2bf(acc[i][j][r] + bs);
        }
      }
  } else {
    // mlp hidden -> gelu -> gel8 (cols 3072..3839; valid < 3788)
#pragma unroll
    for (int i = 0; i < 2; ++i)
#pragma unroll
      for (int j = 0; j < 2; ++j) {
        const int col = bn * 128 + wcol + j * 32 + r32;
        const int c = col - 3072;
        const bool ok = (col < 3788);
        const float bs = ok ? b1[col] : 0.f;
#pragma unroll
        for (int r = 0; r < 16; ++r) {
          const int row = bm * 128 + wrow + i * 32 + 4 * h + (r & 3) + 8 * (r >> 2);
          float y = acc[i][j][r] + bs;
          float ge = ok ? 0.5f * y * (1.f + erff(y * 0.70710678118654752f)) : 0.f;
          gel8[(size_t)row * 768 + c] = f2fp8(ge);
        }
      }
  }
}

// ---------------- proj + mlp fused (64-row tiles): comb[4096][2048] fp8
__global__ __launch_bounds__(256) void k_gemm_pm(
    const u8* __restrict__ xo, const u8* __restrict__ pWt,
    const u8* __restrict__ gel, const u8* __restrict__ mWt,
    u8* __restrict__ comb, const float* __restrict__ projb) {
  __shared__ __align__(16) u8 Alds[3 * 64 * 64];
  __shared__ __align__(16) u8 Blds[3 * 128 * 64];
  const int tid = threadIdx.x, bm = blockIdx.y, bnq = blockIdx.x;
  const u8* A;
  const u8* B;
  int K, colbase;
  const float* bias;
  if (bnq < 8) {
    A = xo + (size_t)bm * 64 * 1024;
    B = pWt + (size_t)bnq * 128 * 1024;
    K = 1024; colbase = bnq * 128; bias = projb;
  } else {
    A = gel + (size_t)bm * 64 * 768;
    B = mWt + (size_t)(bnq - 8) * 128 * 768;
    K = 768; colbase = 1024 + (bnq - 8) * 128; bias = nullptr;
  }
  f32x16 acc[2];
#pragma unroll
  for (int j = 0; j < 2; ++j)
#pragma unroll
    for (int r = 0; r < 16; ++r) acc[j][r] = 0.f;
  gemm_fp8_core64(A, B, K, Alds, Blds, acc, tid);
  const int lane = tid & 63, wave = tid >> 6;
  const int h = lane >> 5, r32 = lane & 31;
  const int wrow = (wave >> 1) * 32, wcol = (wave & 1) * 64;
#pragma unroll
  for (int j = 0; j < 2; ++j) {
    const int col = colbase + wcol + j * 32 + r32;
    const float bs = (bias != nullptr) ? bias[col] : 0.f;
#pragma unroll
    for (int r = 0; r < 16; ++r) {
      const int row = bm * 64 + wrow + 4 * h + (r & 3) + 8 * (r >> 2);
      comb[(size_t)row * 2048 + col] = f2fp8(acc[j][r] + bs);
    }
  }
}

// ---------------- final (64-row tiles): out = x + (comb @ W2t^T + b2) * ls_g
__global__ __launch_bounds__(256) void k_gemm_fin(const u8* __restrict__ comb,
                                                  const u8* __restrict__ W2t,
                                                  float* __restrict__ out,
                                                  const float* __restrict__ b2,
                                                  const float* __restrict__ x,
                                                  const float* __restrict__ lsg) {
  __shared__ __align__(16) u8 Alds[3 * 64 * 64];
  __shared__ __align__(16) u8 Blds[3 * 128 * 64];
  const int tid = threadIdx.x, bm = blockIdx.y, bn = blockIdx.x;
  f32x16 acc[2];
#pragma unroll
  for (int j = 0; j < 2; ++j)
#pragma unroll
    for (int r = 0; r < 16; ++r) acc[j][r] = 0.f;
  gemm_fp8_core64(comb + (size_t)bm * 64 * 2048, W2t + (size_t)bn * 128 * 2048, 2048,
                  Alds, Blds, acc, tid);
  const int lane = tid & 63, wave = tid >> 6;
  const int h = lane >> 5, r32 = lane & 31;
  const int wrow = (wave >> 1) * 32, wcol = (wave & 1) * 64;
#pragma unroll
  for (int j = 0; j < 2; ++j) {
    const int col = bn * 128 + wcol + j * 32 + r32;
    const float bs = b2[col], ls = lsg[col];
#pragma unroll
    for (int r = 0; r < 16; ++r) {
      const int row = bm * 64 + wrow + 4 * h + (r & 3) + 8 * (r >> 2);
      out[(size_t)row * 1024 + col] =
          x[(size_t)row * 1024 + col] + (acc[j][r] + bs) * ls;
    }
  }
}

// ---------------- V^T extraction (only remaining mid-pass work): vtb[bh][d][n]
__global__ __launch_bounds__(256) void k_mid(const u16* __restrict__ f1,
                                             u16* __restrict__ vtb) {
  __shared__ u16 tt[32][33];
  const int tid = threadIdx.x;
  const int t = blockIdx.x;  // [0, 4096)
  const int xq = t & 1, yq = (t >> 1) & 31, z = t >> 6;
  const int b = z >> 4, h = z & 15;
  const int d0 = xq * 32, n0 = yq * 32;
  const int tx = tid & 31, ty = tid >> 5;
#pragma unroll
  for (int j = 0; j < 4; ++j)
    tt[ty + 8 * j][tx] =
        f1[(size_t)(b * 1024 + n0 + ty + 8 * j) * 3840 + 2048 + h * 64 + d0 + tx];
  __syncthreads();
#pragma unroll
  for (int j = 0; j < 4; ++j)
    vtb[(size_t)z * 65536 + (size_t)(d0 + ty + 8 * j) * 1024 + n0 + tx] =
        tt[tx][ty + 8 * j];
}

// ---------------- flash attention v6: v5 zero-barrier structure + T15 two-tile
// pipeline: QK(t+1) MFMAs issue BEFORE softmax/PV(t), so exp(t) VALU overlaps
// QK(t+1) in the matrix pipe within a single wave. Static ping-pong state
// (Sa/Sb, vfA/vfB; 2x-unrolled loop) per rule #20; sched_barrier(0) after each
// lgkmcnt(0) per rule #18. Counted vmcnt (T4), 16KB LDS, grid 2048 x 64thr.
__global__ __launch_bounds__(64) void k_flash(const u16* __restrict__ q,
                                              const u16* __restrict__ k,
                                              const u16* __restrict__ vt,
                                              u8* __restrict__ xo) {
  __shared__ __align__(16) u16 Kl[2][32 * 64];
  __shared__ __align__(16) u16 Vl[2][64 * 32];
  const int lane = threadIdx.x & 63;
  const int l31 = lane & 31, h = lane >> 5;
  const int L = blockIdx.x;
  const int xcd = L & 7, i = L >> 3;
  const int bh = xcd * 8 + (i & 7);
  const int qt = i >> 3;
  const int qrow0 = qt * 32;
  const u16* qb = q + ((size_t)bh * 1024 + qrow0) * 64;
  const u16* kb = k + (size_t)bh * 1024 * 64;
  const u16* vb = vt + (size_t)bh * 64 * 1024;

  u16x8 qf[4];
#pragma unroll
  for (int ds = 0; ds < 4; ++ds)
    qf[ds] = *(const u16x8*)(qb + (size_t)l31 * 64 + ds * 16 + h * 8);
  asm volatile("s_waitcnt vmcnt(0)" ::: "memory");

  f32x16 O[2];
#pragma unroll
  for (int d2 = 0; d2 < 2; ++d2)
#pragma unroll
    for (int r = 0; r < 16; ++r) O[d2][r] = 0.f;
  float lacc = 0.f;

  auto STAGE = [&](int t, int bb) {
#pragma unroll
    for (int p = 0; p < 4; ++p) {
      const int s = lane + 64 * p;
      const int kr = s >> 3, kslot = s & 7;
      const int kc = kslot ^ ((kr ^ (kr >> 3)) & 7);
      load_lds16(kb + (size_t)(t * 32 + kr) * 64 + kc * 8, (u16*)Kl[bb] + s * 8);
      const int vr = s >> 2, vslot = s & 3;
      const int vc = vslot ^ ((vr >> 1) & 3);
      load_lds16(vb + (size_t)vr * 1024 + t * 32 + vc * 8, (u16*)Vl[bb] + s * 8);
    }
  };
  STAGE(0, 0);
  STAGE(1, 1);

  const int swzk = (l31 & 7) ^ ((l31 >> 3) & 3);
  const float C = 0.18033688011112042f;  // 0.125 * log2(e)

  f32x16 Sa, Sb;
  u16x8 vfA[4], vfB[4];

  // read frags of a tile from LDS; kf -> local, vf -> given array
  auto READ_FRAGS = [&](int t, u16x8 (&kf)[4], u16x8 (&vf)[4]) {
    const u16* Kc = (const u16*)Kl[t & 1];
    const u16* Vc = (const u16*)Vl[t & 1];
#pragma unroll
    for (int ds = 0; ds < 4; ++ds)
      kf[ds] = *(const u16x8*)(Kc + l31 * 64 + (((ds * 2 + h) ^ swzk)) * 8);
#pragma unroll
    for (int m = 0; m < 2; ++m)
#pragma unroll
      for (int d2 = 0; d2 < 2; ++d2) {
        const int vr = d2 * 32 + l31;
        const int pos = (m * 2 + h) ^ ((vr >> 1) & 3);
        vf[m * 2 + d2] = *(const u16x8*)(Vc + vr * 32 + pos * 8);
      }
  };

  // prologue: tile 0 -> Sa, vfA
  {
    asm volatile("s_waitcnt vmcnt(8)" ::: "memory");
    u16x8 kf[4];
    READ_FRAGS(0, kf, vfA);
    asm volatile("s_waitcnt lgkmcnt(0)" ::: "memory");
    __builtin_amdgcn_sched_barrier(0);
    STAGE(2, 0);
#pragma unroll
    for (int r = 0; r < 16; ++r) Sa[r] = 0.f;
    __builtin_amdgcn_s_setprio(1);
#pragma unroll
    for (int ds = 0; ds < 4; ++ds) Sa = mfma32(kf[ds], qf[ds], Sa);
    __builtin_amdgcn_s_setprio(0);
  }

  auto TILE = [&](int t, f32x16& Sc, f32x16& Sn, u16x8 (&vc)[4], u16x8 (&vn)[4]) {
    if (t < 31) {
      if (t <= 29)
        asm volatile("s_waitcnt vmcnt(8)" ::: "memory");
      else
        asm volatile("s_waitcnt vmcnt(0)" ::: "memory");
      u16x8 kf[4];
      READ_FRAGS(t + 1, kf, vn);
      asm volatile("s_waitcnt lgkmcnt(0)" ::: "memory");
      __builtin_amdgcn_sched_barrier(0);
      if (t + 3 < 32) STAGE(t + 3, (t + 3) & 1);
#pragma unroll
      for (int r = 0; r < 16; ++r) Sn[r] = 0.f;
      __builtin_amdgcn_s_setprio(1);
#pragma unroll
      for (int ds = 0; ds < 4; ++ds) Sn = mfma32(kf[ds], qf[ds], Sn);
      __builtin_amdgcn_s_setprio(0);
    }
    // softmax + PV of tile t (overlaps with QK(t+1) in the matrix pipe)
#pragma unroll
    for (int r = 0; r < 16; ++r) {
      float pv = exp2_fast(Sc[r] * C);
      Sc[r] = pv;
      lacc += pv;
    }
    __builtin_amdgcn_s_setprio(1);
#pragma unroll
    for (int m = 0; m < 2; ++m) {
      const int ro = m * 8;
      unsigned w0 = cvtpk_bf16(Sc[ro + 0], Sc[ro + 1]);
      unsigned w2 = cvtpk_bf16(Sc[ro + 4], Sc[ro + 5]);
      unsigned w1 = cvtpk_bf16(Sc[ro + 2], Sc[ro + 3]);
      unsigned w3 = cvtpk_bf16(Sc[ro + 6], Sc[ro + 7]);
      plswap(w0, w2);
      plswap(w1, w3);
      i32x4 aw;
      aw[0] = (int)w0; aw[1] = (int)w1; aw[2] = (int)w2; aw[3] = (int)w3;
      const u16x8 pa = __builtin_bit_cast(u16x8, aw);
#pragma unroll
      for (int d2 = 0; d2 < 2; ++d2) O[d2] = mfma32(pa, vc[m * 2 + d2], O[d2]);
    }
    __builtin_amdgcn_s_setprio(0);
  };

  for (int t = 0; t < 32; t += 2) {
    TILE(t, Sa, Sb, vfA, vfB);
    TILE(t + 1, Sb, Sa, vfB, vfA);
  }

  lacc += __shfl_xor(lacc, 32);
  const float inv = 1.f / lacc;
  const int b = bh >> 4, hh = bh & 15;
#pragma unroll
  for (int r = 0; r < 16; ++r) {
    const int qr = (r & 3) + 8 * (r >> 2) + 4 * h;
    const float invr = __shfl(inv, qr);
    u8* orow = xo + (size_t)(b * 1024 + qrow0 + qr) * 1024 + hh * 64;
    orow[l31] = f2fp8(O[0][r] * invr);
    orow[32 + l31] = f2fp8(O[1][r] * invr);
  }
}

extern "C" void kernel_launch(void* const* d_in, const int* in_sizes, int n_in,
                              void* d_out, int out_size, void* d_ws, size_t ws_size,
                              hipStream_t stream) {
  (void)in_sizes; (void)n_in; (void)out_size; (void)ws_size;
  const float* x      = (const float*)d_in[0];
  const float* norm_g = (const float*)d_in[1];
  const float* norm_b = (const float*)d_in[2];
  const float* W1     = (const float*)d_in[3];
  const float* b1     = (const float*)d_in[4];
  const float* qn_g   = (const float*)d_in[5];
  const float* qn_b   = (const float*)d_in[6];
  const float* kn_g   = (const float*)d_in[7];
  const float* kn_b   = (const float*)d_in[8];
  const float* projW  = (const float*)d_in[9];
  const float* projb  = (const float*)d_in[10];
  const float* mlpW   = (const float*)d_in[11];
  const float* W2     = (const float*)d_in[12];
  const float* b2     = (const float*)d_in[13];
  const float* ls_g   = (const float*)d_in[14];

  char* ws = (char*)d_ws;
  u8*  W1t8 = (u8*)(ws + 0);           // [3840][1024]  3,932,160
  u8*  pWt8 = (u8*)(ws + 3932160);     // [1024][1024]  1,048,576
  u8*  mWt8 = (u8*)(ws + 4980736);     // [1024][768]     786,432
  u8*  W2t8 = (u8*)(ws + 5767168);     // [1024][2048]  2,097,152
  u8*  nx8  = (u8*)(ws + 7864320);     // [4096][1024]  4,194,304 (then xo8)
  u16* f1   = (u16*)(ws + 12058624);   // [4096][3840] 31,457,280 bf16 (V region; then comb fp8)
  u16* qbuf = (u16*)(ws + 43515904);   // [64][1024][64] 8,388,608
  u16* kbuf = (u16*)(ws + 51904512);   // [64][1024][64] 8,388,608
  u16* vtb  = (u16*)(ws + 60293120);   // [64][64][1024] 8,388,608
  u8*  gel8 = (u8*)(ws + 68681728);    // [4096][768]   3,145,728

  k_pre<<<11776, 256, 0, stream>>>(W1, projW, mlpW, W2, W1t8, pWt8, mWt8, W2t8,
                                   x, norm_g, norm_b, nx8);
  k_gemm1<<<dim3(30, 32), 256, 0, stream>>>(nx8, W1t8, f1, b1, qn_g, qn_b, kn_g,
                                            kn_b, qbuf, kbuf, gel8);
  k_mid<<<4096, 256, 0, stream>>>(f1, vtb);
  k_flash<<<2048, 64, 0, stream>>>(qbuf, kbuf, vtb, nx8);
  k_gemm_pm<<<dim3(16, 64), 256, 0, stream>>>(nx8, pWt8, gel8, mWt8, (u8*)f1, projb);
  k_gemm_fin<<<dim3(8, 64), 256, 0, stream>>>((u8*)f1, W2t8, (float*)d_out, b2, x,
                                              ls_g);
}

// Round 7
// 228.526 us; speedup vs baseline: 1.0240x; 1.0142x over previous
//
#include <hip/hip_runtime.h>
#include <cstdint>
#include <cstddef>

typedef unsigned short u16;
typedef unsigned char u8;
typedef __attribute__((ext_vector_type(8))) u16 u16x8;
typedef __attribute__((ext_vector_type(8))) __bf16 bf16x8;
typedef __attribute__((ext_vector_type(4))) float f32x4;
typedef __attribute__((ext_vector_type(16))) float f32x16;
typedef __attribute__((ext_vector_type(4))) int i32x4;
typedef __attribute__((ext_vector_type(8))) int i32x8;
typedef __attribute__((ext_vector_type(2))) int i32x2;

__device__ __forceinline__ u16 f2bf(float f) {
  unsigned u = __builtin_bit_cast(unsigned, f);
  return (u16)((u + 0x7FFFu + ((u >> 16) & 1u)) >> 16);
}
__device__ __forceinline__ float bf2f(u16 h) {
  return __builtin_bit_cast(float, (unsigned)h << 16);
}
__device__ __forceinline__ u8 f2fp8(float f) {
  return (u8)(__builtin_amdgcn_cvt_pk_fp8_f32(f, 0.f, 0, false) & 0xFF);
}
__device__ __forceinline__ f32x16 mfma32(u16x8 a, u16x8 b, f32x16 c) {
  return __builtin_amdgcn_mfma_f32_32x32x16_bf16(
      __builtin_bit_cast(bf16x8, a), __builtin_bit_cast(bf16x8, b), c, 0, 0, 0);
}
__device__ __forceinline__ unsigned cvtpk_bf16(float lo, float hi) {
  unsigned r;
  asm("v_cvt_pk_bf16_f32 %0, %1, %2" : "=v"(r) : "v"(lo), "v"(hi));
  return r;
}
__device__ __forceinline__ float exp2_fast(float x) {
  float r;
  asm("v_exp_f32 %0, %1" : "=v"(r) : "v"(x));
  return r;
}
__device__ __forceinline__ void plswap(unsigned& a, unsigned& b) {
  i32x2 r = __builtin_amdgcn_permlane32_swap((int)a, (int)b, false, false);
  a = (unsigned)r[0];
  b = (unsigned)r[1];
}
__device__ __forceinline__ void load_lds16(const void* g, void* l) {
  __builtin_amdgcn_global_load_lds(
      (const __attribute__((address_space(1))) void*)g,
      (__attribute__((address_space(3))) void*)l, 16, 0, 0);
}

// ---------------- fused pre-pass: 4 weight transposes (fp8) + x LayerNorm (fp8)
__global__ __launch_bounds__(256) void k_pre(
    const float* __restrict__ W1, const float* __restrict__ projW,
    const float* __restrict__ mlpW, const float* __restrict__ W2,
    u8* __restrict__ W1t, u8* __restrict__ pWt, u8* __restrict__ mWt,
    u8* __restrict__ W2t, const float* __restrict__ x,
    const float* __restrict__ g, const float* __restrict__ b,
    u8* __restrict__ nx8) {
  __shared__ float t[32][33];
  __shared__ float red[8];
  const int L = blockIdx.x;
  const int tid = threadIdx.x;
  if (L < 7680) {
    const float* src;
    u8* dst;
    int R, C, dR, dC, bx, by;
    if (L < 3840) {
      src = W1; dst = W1t; R = 1024; C = 3788; dR = 1024; dC = 3840;
      bx = L % 120; by = L / 120;
    } else if (L < 4864) {
      int tq = L - 3840;
      src = projW; dst = pWt; R = 1024; C = 1024; dR = 1024; dC = 1024;
      bx = tq & 31; by = tq >> 5;
    } else if (L < 5632) {
      int tq = L - 4864;
      src = mlpW; dst = mWt; R = 716; C = 1024; dR = 768; dC = 1024;
      bx = tq & 31; by = tq >> 5;
    } else {
      int tq = L - 5632;
      src = W2; dst = W2t; R = 2048; C = 1024; dR = 2048; dC = 1024;
      bx = tq & 31; by = tq >> 5;
    }
    const int n0 = bx * 32, k0 = by * 32;
    const int tx = tid & 31, ty = tid >> 5;
#pragma unroll
    for (int j = 0; j < 4; ++j) {
      int kk = k0 + ty + 8 * j, nn = n0 + tx;
      float v = (kk < R && nn < C) ? src[(size_t)kk * C + nn] : 0.f;
      t[ty + 8 * j][tx] = v;
    }
    __syncthreads();
#pragma unroll
    for (int j = 0; j < 4; ++j) {
      int nn = n0 + ty + 8 * j, kk = k0 + tx;
      if (nn < dC && kk < dR) dst[(size_t)nn * dR + kk] = f2fp8(t[tx][ty + 8 * j]);
    }
  } else {
    const int row = L - 7680;
    float4 v = ((const float4*)(x + (size_t)row * 1024))[tid];
    float s = v.x + v.y + v.z + v.w;
    float ss = v.x * v.x + v.y * v.y + v.z * v.z + v.w * v.w;
#pragma unroll
    for (int off = 1; off < 64; off <<= 1) {
      s += __shfl_xor(s, off);
      ss += __shfl_xor(ss, off);
    }
    const int wid = tid >> 6, lane = tid & 63;
    if (lane == 0) { red[wid] = s; red[4 + wid] = ss; }
    __syncthreads();
    s = red[0] + red[1] + red[2] + red[3];
    ss = red[4] + red[5] + red[6] + red[7];
    const float mean = s * (1.f / 1024.f);
    const float var = ss * (1.f / 1024.f) - mean * mean;
    const float rstd = rsqrtf(var + 1e-5f);
    float4 gv = ((const float4*)g)[tid];
    float4 bv = ((const float4*)b)[tid];
    float y0 = (v.x - mean) * rstd * gv.x + bv.x;
    float y1 = (v.y - mean) * rstd * gv.y + bv.y;
    float y2 = (v.z - mean) * rstd * gv.z + bv.z;
    float y3 = (v.w - mean) * rstd * gv.w + bv.w;
    int pk = __builtin_amdgcn_cvt_pk_fp8_f32(y0, y1, 0, false);
    pk = __builtin_amdgcn_cvt_pk_fp8_f32(y2, y3, pk, true);
    ((int*)(nx8 + (size_t)row * 1024))[tid] = pk;
  }
}

// ---------------- MX-fp8 GEMM core 128x128, 2-buffer counted-vmcnt pipeline:
// read frags(buf cur) -> lgkmcnt(0) -> barrier -> STAGE(kt+2 -> cur) -> MFMA ->
// vmcnt(4) -> barrier. Tile kt+1 stays in flight the whole iteration (issued a
// full iter earlier); vmcnt never drains to 0 mid-loop. 32KB LDS -> 5 blocks/CU.
__device__ __forceinline__ void gemm_fp8_core(const u8* __restrict__ A,
                                              const u8* __restrict__ B, int K,
                                              u8* Alds, u8* Blds,
                                              f32x16 (&acc)[2][2], int tid) {
  const int lane = tid & 63, wave = tid >> 6;
  const int h = lane >> 5, r32 = lane & 31;
  const int wrow = (wave >> 1) * 64, wcol = (wave & 1) * 64;
  const int srow0 = tid >> 2, spos = tid & 3;
  const int nk = K >> 6;
  auto STAGE = [&](int t, int bb) {
#pragma unroll
    for (int p = 0; p < 2; ++p) {
      const int row = p * 64 + srow0;
      const int c = spos ^ ((row >> 1) & 3);
      const size_t go = (size_t)row * K + (size_t)t * 64 + c * 16;
      load_lds16(A + go, Alds + bb * 8192 + (p * 256 + tid) * 16);
      load_lds16(B + go, Blds + bb * 8192 + (p * 256 + tid) * 16);
    }
  };
  STAGE(0, 0);
  STAGE(1, 1);
  asm volatile("s_waitcnt vmcnt(4)" ::: "memory");
  __builtin_amdgcn_s_barrier();
  for (int kt = 0; kt < nk; ++kt) {
    const int cur = kt & 1;
    const u8* Ac = Alds + cur * 8192;
    const u8* Bc = Blds + cur * 8192;
    i32x8 af[2], bf[2];
#pragma unroll
    for (int t = 0; t < 2; ++t) {
      {
        const int row = wrow + t * 32 + r32;
        const int sw = (row >> 1) & 3;
        i32x4 lo = *(const i32x4*)(Ac + row * 64 + ((2 * h) ^ sw) * 16);
        i32x4 hi = *(const i32x4*)(Ac + row * 64 + ((2 * h + 1) ^ sw) * 16);
        i32x8 a;
        a[0] = lo[0]; a[1] = lo[1]; a[2] = lo[2]; a[3] = lo[3];
        a[4] = hi[0]; a[5] = hi[1]; a[6] = hi[2]; a[7] = hi[3];
        af[t] = a;
      }
      {
        const int row = wcol + t * 32 + r32;
        const int sw = (row >> 1) & 3;
        i32x4 lo = *(const i32x4*)(Bc + row * 64 + ((2 * h) ^ sw) * 16);
        i32x4 hi = *(const i32x4*)(Bc + row * 64 + ((2 * h + 1) ^ sw) * 16);
        i32x8 b8;
        b8[0] = lo[0]; b8[1] = lo[1]; b8[2] = lo[2]; b8[3] = lo[3];
        b8[4] = hi[0]; b8[5] = hi[1]; b8[6] = hi[2]; b8[7] = hi[3];
        bf[t] = b8;
      }
    }
    // frags in regs; all waves done reading buf[cur] -> safe to overwrite
    asm volatile("s_waitcnt lgkmcnt(0)" ::: "memory");
    __builtin_amdgcn_sched_barrier(0);
    __builtin_amdgcn_s_barrier();
    if (kt + 2 < nk) STAGE(kt + 2, cur);
#pragma unroll
    for (int i = 0; i < 2; ++i)
#pragma unroll
      for (int j = 0; j < 2; ++j)
        acc[i][j] = __builtin_amdgcn_mfma_scale_f32_32x32x64_f8f6f4(
            af[i], bf[j], acc[i][j], 0, 0, 0, 0x7F7F7F7F, 0, 0x7F7F7F7F);
    if (kt + 1 < nk) {
      if (kt + 2 < nk)
        asm volatile("s_waitcnt vmcnt(4)" ::: "memory");
      else
        asm volatile("s_waitcnt vmcnt(0)" ::: "memory");
      __builtin_amdgcn_s_barrier();
    }
  }
}

// ---------------- MX-fp8 GEMM core 64(M)x128(N), 2-buffer counted-vmcnt.
// 3 staging loads/thread/tile -> steady wait vmcnt(3). 24KB LDS -> 6 blocks/CU.
__device__ __forceinline__ void gemm_fp8_core64(const u8* __restrict__ A,
                                                const u8* __restrict__ B, int K,
                                                u8* Alds, u8* Blds,
                                                f32x16 (&acc)[2], int tid) {
  const int lane = tid & 63, wave = tid >> 6;
  const int h = lane >> 5, r32 = lane & 31;
  const int wrow = (wave >> 1) * 32, wcol = (wave & 1) * 64;
  const int nk = K >> 6;
  const int ra = tid >> 2, posa = tid & 3;
  const int ca = posa ^ ((ra >> 1) & 3);
  auto STAGE = [&](int t, int bb) {
    const size_t k0 = (size_t)t * 64;
    load_lds16(A + (size_t)ra * K + k0 + ca * 16, Alds + bb * 4096 + tid * 16);
#pragma unroll
    for (int p = 0; p < 2; ++p) {
      const int s = tid + 256 * p;
      const int r = s >> 2, pos = s & 3;
      const int c = pos ^ ((r >> 1) & 3);
      load_lds16(B + (size_t)r * K + k0 + c * 16, Blds + bb * 8192 + s * 16);
    }
  };
  STAGE(0, 0);
  STAGE(1, 1);
  asm volatile("s_waitcnt vmcnt(3)" ::: "memory");
  __builtin_amdgcn_s_barrier();
  for (int kt = 0; kt < nk; ++kt) {
    const int cur = kt & 1;
    const u8* Ac = Alds + cur * 4096;
    const u8* Bc = Blds + cur * 8192;
    i32x8 af, bf[2];
    {
      const int row = wrow + r32;
      const int sw = (row >> 1) & 3;
      i32x4 lo = *(const i32x4*)(Ac + row * 64 + ((2 * h) ^ sw) * 16);
      i32x4 hi = *(const i32x4*)(Ac + row * 64 + ((2 * h + 1) ^ sw) * 16);
      af[0] = lo[0]; af[1] = lo[1]; af[2] = lo[2]; af[3] = lo[3];
      af[4] = hi[0]; af[5] = hi[1]; af[6] = hi[2]; af[7] = hi[3];
    }
#pragma unroll
    for (int t = 0; t < 2; ++t) {
      const int row = wcol + t * 32 + r32;
      const int sw = (row >> 1) & 3;
      i32x4 lo = *(const i32x4*)(Bc + row * 64 + ((2 * h) ^ sw) * 16);
      i32x4 hi = *(const i32x4*)(Bc + row * 64 + ((2 * h + 1) ^ sw) * 16);
      i32x8 b8;
      b8[0] = lo[0]; b8[1] = lo[1]; b8[2] = lo[2]; b8[3] = lo[3];
      b8[4] = hi[0]; b8[5] = hi[1]; b8[6] = hi[2]; b8[7] = hi[3];
      bf[t] = b8;
    }
    asm volatile("s_waitcnt lgkmcnt(0)" ::: "memory");
    __builtin_amdgcn_sched_barrier(0);
    __builtin_amdgcn_s_barrier();
    if (kt + 2 < nk) STAGE(kt + 2, cur);
#pragma unroll
    for (int j = 0; j < 2; ++j)
      acc[j] = __builtin_amdgcn_mfma_scale_f32_32x32x64_f8f6f4(
          af, bf[j], acc[j], 0, 0, 0, 0x7F7F7F7F, 0, 0x7F7F7F7F);
    if (kt + 1 < nk) {
      if (kt + 2 < nk)
        asm volatile("s_waitcnt vmcnt(3)" ::: "memory");
      else
        asm volatile("s_waitcnt vmcnt(0)" ::: "memory");
      __builtin_amdgcn_s_barrier();
    }
  }
}

// ---------------- GEMM1 + fused epilogue:
// bn<16  : q/k per-head LayerNorm (d=64 = one wave's 64-col tile) -> qbuf/kbuf bf16
// bn<24  : V region -> f1 bf16 (consumed by VT transpose)
// bn>=24 : mlp hidden -> gelu -> gel8 fp8
__global__ __launch_bounds__(256) void k_gemm1(
    const u8* __restrict__ nx8, const u8* __restrict__ W1t, u16* __restrict__ f1,
    const float* __restrict__ b1, const float* __restrict__ qg,
    const float* __restrict__ qb_, const float* __restrict__ kg,
    const float* __restrict__ kb_, u16* __restrict__ qbuf, u16* __restrict__ kbuf,
    u8* __restrict__ gel8) {
  __shared__ __align__(16) u8 Alds[2 * 128 * 64];
  __shared__ __align__(16) u8 Blds[2 * 128 * 64];
  const int tid = threadIdx.x, bm = blockIdx.y, bn = blockIdx.x;
  f32x16 acc[2][2];
#pragma unroll
  for (int i = 0; i < 2; ++i)
#pragma unroll
    for (int j = 0; j < 2; ++j)
#pragma unroll
      for (int r = 0; r < 16; ++r) acc[i][j][r] = 0.f;
  gemm_fp8_core(nx8 + (size_t)bm * 128 * 1024, W1t + (size_t)bn * 128 * 1024, 1024,
                Alds, Blds, acc, tid);
  const int lane = tid & 63, wave = tid >> 6;
  const int h = lane >> 5, r32 = lane & 31;
  const int wrow = (wave >> 1) * 64, wcol = (wave & 1) * 64;
  if (bn < 16) {
    const int wc = bn * 128 + wcol;     // multiple of 64, < 2048
    const int which = wc >> 10;         // 0 = q, 1 = k
    const int head = (wc >> 6) & 15;
    const float* g = which ? kg : qg;
    const float* bb = which ? kb_ : qb_;
    const float g0 = g[r32], g1 = g[32 + r32];
    const float be0 = bb[r32], be1 = bb[32 + r32];
    const float bias0 = b1[wc + r32], bias1 = b1[wc + 32 + r32];
    u16* dst = which ? kbuf : qbuf;
#pragma unroll
    for (int i = 0; i < 2; ++i)
#pragma unroll
      for (int r = 0; r < 16; ++r) {
        float v0 = acc[i][0][r] + bias0;
        float v1 = acc[i][1][r] + bias1;
        float s = v0 + v1, ss = v0 * v0 + v1 * v1;
#pragma unroll
        for (int off = 1; off < 32; off <<= 1) {
          s += __shfl_xor(s, off);
          ss += __shfl_xor(ss, off);
        }
        const float mean = s * (1.f / 64.f);
        const float var = ss * (1.f / 64.f) - mean * mean;
        const float rstd = rsqrtf(var + 1e-5f);
        const int row = bm * 128 + wrow + i * 32 + 4 * h + (r & 3) + 8 * (r >> 2);
        const int b = row >> 10, n = row & 1023;
        u16* orow = dst + ((size_t)(b * 16 + head) * 1024 + n) * 64;
        orow[r32] = f2bf((v0 - mean) * rstd * g0 + be0);
        orow[32 + r32] = f2bf((v1 - mean) * rstd * g1 + be1);
      }
  } else if (bn < 24) {
#pragma unroll
    for (int i = 0; i < 2; ++i)
#pragma unroll
      for (int j = 0; j < 2; ++j) {
        const int col = bn * 128 + wcol + j * 32 + r32;
        const float bs = b1[col];
#pragma unroll
        for (int r = 0; r < 16; ++r) {
          const int row = bm * 128 + wrow + i * 32 + 4 * h + (r & 3) + 8 * (r >> 2);
          f1[(size_t)row * 3840 + col] = f2bf(acc[i][j][r] + bs);
        }
      }
  } else {
#pragma unroll
    for (int i = 0; i < 2; ++i)
#pragma unroll
      for (int j = 0; j < 2; ++j) {
        const int col = bn * 128 + wcol + j * 32 + r32;
        const int c = col - 3072;
        const bool ok = (col < 3788);
        const float bs = ok ? b1[col] : 0.f;
#pragma unroll
        for (int r = 0; r < 16; ++r) {
          const int row = bm * 128 + wrow + i * 32 + 4 * h + (r & 3) + 8 * (r >> 2);
          float y = acc[i][j][r] + bs;
          float ge = ok ? 0.5f * y * (1.f + erff(y * 0.70710678118654752f)) : 0.f;
          gel8[(size_t)row * 768 + c] = f2fp8(ge);
        }
      }
  }
}

// ---------------- proj + mlp fused (64-row tiles): comb[4096][2048] fp8
__global__ __launch_bounds__(256) void k_gemm_pm(
    const u8* __restrict__ xo, const u8* __restrict__ pWt,
    const u8* __restrict__ gel, const u8* __restrict__ mWt,
    u8* __restrict__ comb, const float* __restrict__ projb) {
  __shared__ __align__(16) u8 Alds[2 * 64 * 64];
  __shared__ __align__(16) u8 Blds[2 * 128 * 64];
  const int tid = threadIdx.x, bm = blockIdx.y, bnq = blockIdx.x;
  const u8* A;
  const u8* B;
  int K, colbase;
  const float* bias;
  if (bnq < 8) {
    A = xo + (size_t)bm * 64 * 1024;
    B = pWt + (size_t)bnq * 128 * 1024;
    K = 1024; colbase = bnq * 128; bias = projb;
  } else {
    A = gel + (size_t)bm * 64 * 768;
    B = mWt + (size_t)(bnq - 8) * 128 * 768;
    K = 768; colbase = 1024 + (bnq - 8) * 128; bias = nullptr;
  }
  f32x16 acc[2];
#pragma unroll
  for (int j = 0; j < 2; ++j)
#pragma unroll
    for (int r = 0; r < 16; ++r) acc[j][r] = 0.f;
  gemm_fp8_core64(A, B, K, Alds, Blds, acc, tid);
  const int lane = tid & 63, wave = tid >> 6;
  const int h = lane >> 5, r32 = lane & 31;
  const int wrow = (wave >> 1) * 32, wcol = (wave & 1) * 64;
#pragma unroll
  for (int j = 0; j < 2; ++j) {
    const int col = colbase + wcol + j * 32 + r32;
    const float bs = (bias != nullptr) ? bias[col] : 0.f;
#pragma unroll
    for (int r = 0; r < 16; ++r) {
      const int row = bm * 64 + wrow + 4 * h + (r & 3) + 8 * (r >> 2);
      comb[(size_t)row * 2048 + col] = f2fp8(acc[j][r] + bs);
    }
  }
}

// ---------------- final (64-row tiles): out = x + (comb @ W2t^T + b2) * ls_g
__global__ __launch_bounds__(256) void k_gemm_fin(const u8* __restrict__ comb,
                                                  const u8* __restrict__ W2t,
                                                  float* __restrict__ out,
                                                  const float* __restrict__ b2,
                                                  const float* __restrict__ x,
                                                  const float* __restrict__ lsg) {
  __shared__ __align__(16) u8 Alds[2 * 64 * 64];
  __shared__ __align__(16) u8 Blds[2 * 128 * 64];
  const int tid = threadIdx.x, bm = blockIdx.y, bn = blockIdx.x;
  f32x16 acc[2];
#pragma unroll
  for (int j = 0; j < 2; ++j)
#pragma unroll
    for (int r = 0; r < 16; ++r) acc[j][r] = 0.f;
  gemm_fp8_core64(comb + (size_t)bm * 64 * 2048, W2t + (size_t)bn * 128 * 2048, 2048,
                  Alds, Blds, acc, tid);
  const int lane = tid & 63, wave = tid >> 6;
  const int h = lane >> 5, r32 = lane & 31;
  const int wrow = (wave >> 1) * 32, wcol = (wave & 1) * 64;
#pragma unroll
  for (int j = 0; j < 2; ++j) {
    const int col = bn * 128 + wcol + j * 32 + r32;
    const float bs = b2[col], ls = lsg[col];
#pragma unroll
    for (int r = 0; r < 16; ++r) {
      const int row = bm * 64 + wrow + 4 * h + (r & 3) + 8 * (r >> 2);
      out[(size_t)row * 1024 + col] =
          x[(size_t)row * 1024 + col] + (acc[j][r] + bs) * ls;
    }
  }
}

// ---------------- V^T extraction (only remaining mid-pass work): vtb[bh][d][n]
__global__ __launch_bounds__(256) void k_mid(const u16* __restrict__ f1,
                                             u16* __restrict__ vtb) {
  __shared__ u16 tt[32][33];
  const int tid = threadIdx.x;
  const int t = blockIdx.x;  // [0, 4096)
  const int xq = t & 1, yq = (t >> 1) & 31, z = t >> 6;
  const int b = z >> 4, h = z & 15;
  const int d0 = xq * 32, n0 = yq * 32;
  const int tx = tid & 31, ty = tid >> 5;
#pragma unroll
  for (int j = 0; j < 4; ++j)
    tt[ty + 8 * j][tx] =
        f1[(size_t)(b * 1024 + n0 + ty + 8 * j) * 3840 + 2048 + h * 64 + d0 + tx];
  __syncthreads();
#pragma unroll
  for (int j = 0; j < 4; ++j)
    vtb[(size_t)z * 65536 + (size_t)(d0 + ty + 8 * j) * 1024 + n0 + tx] =
        tt[tx][ty + 8 * j];
}

// ---------------- flash attention v6: zero-barrier 1-wave blocks + T15 two-tile
// pipeline (QK(t+1) before softmax/PV(t)); counted vmcnt (T4); in-register P
// (cvt_pk + permlane32_swap, T12). 16KB LDS, grid 2048 x 64thr.
__global__ __launch_bounds__(64) void k_flash(const u16* __restrict__ q,
                                              const u16* __restrict__ k,
                                              const u16* __restrict__ vt,
                                              u8* __restrict__ xo) {
  __shared__ __align__(16) u16 Kl[2][32 * 64];
  __shared__ __align__(16) u16 Vl[2][64 * 32];
  const int lane = threadIdx.x & 63;
  const int l31 = lane & 31, h = lane >> 5;
  const int L = blockIdx.x;
  const int xcd = L & 7, i = L >> 3;
  const int bh = xcd * 8 + (i & 7);
  const int qt = i >> 3;
  const int qrow0 = qt * 32;
  const u16* qb = q + ((size_t)bh * 1024 + qrow0) * 64;
  const u16* kb = k + (size_t)bh * 1024 * 64;
  const u16* vb = vt + (size_t)bh * 64 * 1024;

  u16x8 qf[4];
#pragma unroll
  for (int ds = 0; ds < 4; ++ds)
    qf[ds] = *(const u16x8*)(qb + (size_t)l31 * 64 + ds * 16 + h * 8);
  asm volatile("s_waitcnt vmcnt(0)" ::: "memory");

  f32x16 O[2];
#pragma unroll
  for (int d2 = 0; d2 < 2; ++d2)
#pragma unroll
    for (int r = 0; r < 16; ++r) O[d2][r] = 0.f;
  float lacc = 0.f;

  auto STAGE = [&](int t, int bb) {
#pragma unroll
    for (int p = 0; p < 4; ++p) {
      const int s = lane + 64 * p;
      const int kr = s >> 3, kslot = s & 7;
      const int kc = kslot ^ ((kr ^ (kr >> 3)) & 7);
      load_lds16(kb + (size_t)(t * 32 + kr) * 64 + kc * 8, (u16*)Kl[bb] + s * 8);
      const int vr = s >> 2, vslot = s & 3;
      const int vc = vslot ^ ((vr >> 1) & 3);
      load_lds16(vb + (size_t)vr * 1024 + t * 32 + vc * 8, (u16*)Vl[bb] + s * 8);
    }
  };
  STAGE(0, 0);
  STAGE(1, 1);

  const int swzk = (l31 & 7) ^ ((l31 >> 3) & 3);
  const float C = 0.18033688011112042f;  // 0.125 * log2(e)

  f32x16 Sa, Sb;
  u16x8 vfA[4], vfB[4];

  auto READ_FRAGS = [&](int t, u16x8 (&kf)[4], u16x8 (&vf)[4]) {
    const u16* Kc = (const u16*)Kl[t & 1];
    const u16* Vc = (const u16*)Vl[t & 1];
#pragma unroll
    for (int ds = 0; ds < 4; ++ds)
      kf[ds] = *(const u16x8*)(Kc + l31 * 64 + (((ds * 2 + h) ^ swzk)) * 8);
#pragma unroll
    for (int m = 0; m < 2; ++m)
#pragma unroll
      for (int d2 = 0; d2 < 2; ++d2) {
        const int vr = d2 * 32 + l31;
        const int pos = (m * 2 + h) ^ ((vr >> 1) & 3);
        vf[m * 2 + d2] = *(const u16x8*)(Vc + vr * 32 + pos * 8);
      }
  };

  // prologue: tile 0 -> Sa, vfA
  {
    asm volatile("s_waitcnt vmcnt(8)" ::: "memory");
    u16x8 kf[4];
    READ_FRAGS(0, kf, vfA);
    asm volatile("s_waitcnt lgkmcnt(0)" ::: "memory");
    __builtin_amdgcn_sched_barrier(0);
    STAGE(2, 0);
#pragma unroll
    for (int r = 0; r < 16; ++r) Sa[r] = 0.f;
    __builtin_amdgcn_s_setprio(1);
#pragma unroll
    for (int ds = 0; ds < 4; ++ds) Sa = mfma32(kf[ds], qf[ds], Sa);
    __builtin_amdgcn_s_setprio(0);
  }

  auto TILE = [&](int t, f32x16& Sc, f32x16& Sn, u16x8 (&vc)[4], u16x8 (&vn)[4]) {
    if (t < 31) {
      if (t <= 29)
        asm volatile("s_waitcnt vmcnt(8)" ::: "memory");
      else
        asm volatile("s_waitcnt vmcnt(0)" ::: "memory");
      u16x8 kf[4];
      READ_FRAGS(t + 1, kf, vn);
      asm volatile("s_waitcnt lgkmcnt(0)" ::: "memory");
      __builtin_amdgcn_sched_barrier(0);
      if (t + 3 < 32) STAGE(t + 3, (t + 3) & 1);
#pragma unroll
      for (int r = 0; r < 16; ++r) Sn[r] = 0.f;
      __builtin_amdgcn_s_setprio(1);
#pragma unroll
      for (int ds = 0; ds < 4; ++ds) Sn = mfma32(kf[ds], qf[ds], Sn);
      __builtin_amdgcn_s_setprio(0);
    }
#pragma unroll
    for (int r = 0; r < 16; ++r) {
      float pv = exp2_fast(Sc[r] * C);
      Sc[r] = pv;
      lacc += pv;
    }
    __builtin_amdgcn_s_setprio(1);
#pragma unroll
    for (int m = 0; m < 2; ++m) {
      const int ro = m * 8;
      unsigned w0 = cvtpk_bf16(Sc[ro + 0], Sc[ro + 1]);
      unsigned w2 = cvtpk_bf16(Sc[ro + 4], Sc[ro + 5]);
      unsigned w1 = cvtpk_bf16(Sc[ro + 2], Sc[ro + 3]);
      unsigned w3 = cvtpk_bf16(Sc[ro + 6], Sc[ro + 7]);
      plswap(w0, w2);
      plswap(w1, w3);
      i32x4 aw;
      aw[0] = (int)w0; aw[1] = (int)w1; aw[2] = (int)w2; aw[3] = (int)w3;
      const u16x8 pa = __builtin_bit_cast(u16x8, aw);
#pragma unroll
      for (int d2 = 0; d2 < 2; ++d2) O[d2] = mfma32(pa, vc[m * 2 + d2], O[d2]);
    }
    __builtin_amdgcn_s_setprio(0);
  };

  for (int t = 0; t < 32; t += 2) {
    TILE(t, Sa, Sb, vfA, vfB);
    TILE(t + 1, Sb, Sa, vfB, vfA);
  }

  lacc += __shfl_xor(lacc, 32);
  const float inv = 1.f / lacc;
  const int b = bh >> 4, hh = bh & 15;
#pragma unroll
  for (int r = 0; r < 16; ++r) {
    const int qr = (r & 3) + 8 * (r >> 2) + 4 * h;
    const float invr = __shfl(inv, qr);
    u8* orow = xo + (size_t)(b * 1024 + qrow0 + qr) * 1024 + hh * 64;
    orow[l31] = f2fp8(O[0][r] * invr);
    orow[32 + l31] = f2fp8(O[1][r] * invr);
  }
}

extern "C" void kernel_launch(void* const* d_in, const int* in_sizes, int n_in,
                              void* d_out, int out_size, void* d_ws, size_t ws_size,
                              hipStream_t stream) {
  (void)in_sizes; (void)n_in; (void)out_size; (void)ws_size;
  const float* x      = (const float*)d_in[0];
  const float* norm_g = (const float*)d_in[1];
  const float* norm_b = (const float*)d_in[2];
  const float* W1     = (const float*)d_in[3];
  const float* b1     = (const float*)d_in[4];
  const float* qn_g   = (const float*)d_in[5];
  const float* qn_b   = (const float*)d_in[6];
  const float* kn_g   = (const float*)d_in[7];
  const float* kn_b   = (const float*)d_in[8];
  const float* projW  = (const float*)d_in[9];
  const float* projb  = (const float*)d_in[10];
  const float* mlpW   = (const float*)d_in[11];
  const float* W2     = (const float*)d_in[12];
  const float* b2     = (const float*)d_in[13];
  const float* ls_g   = (const float*)d_in[14];

  char* ws = (char*)d_ws;
  u8*  W1t8 = (u8*)(ws + 0);           // [3840][1024]  3,932,160
  u8*  pWt8 = (u8*)(ws + 3932160);     // [1024][1024]  1,048,576
  u8*  mWt8 = (u8*)(ws + 4980736);     // [1024][768]     786,432
  u8*  W2t8 = (u8*)(ws + 5767168);     // [1024][2048]  2,097,152
  u8*  nx8  = (u8*)(ws + 7864320);     // [4096][1024]  4,194,304 (then xo8)
  u16* f1   = (u16*)(ws + 12058624);   // [4096][3840] 31,457,280 bf16 (V region; then comb fp8)
  u16* qbuf = (u16*)(ws + 43515904);   // [64][1024][64] 8,388,608
  u16* kbuf = (u16*)(ws + 51904512);   // [64][1024][64] 8,388,608
  u16* vtb  = (u16*)(ws + 60293120);   // [64][64][1024] 8,388,608
  u8*  gel8 = (u8*)(ws + 68681728);    // [4096][768]   3,145,728

  k_pre<<<11776, 256, 0, stream>>>(W1, projW, mlpW, W2, W1t8, pWt8, mWt8, W2t8,
                                   x, norm_g, norm_b, nx8);
  k_gemm1<<<dim3(30, 32), 256, 0, stream>>>(nx8, W1t8, f1, b1, qn_g, qn_b, kn_g,
                                            kn_b, qbuf, kbuf, gel8);
  k_mid<<<4096, 256, 0, stream>>>(f1, vtb);
  k_flash<<<2048, 64, 0, stream>>>(qbuf, kbuf, vtb, nx8);
  k_gemm_pm<<<dim3(16, 64), 256, 0, stream>>>(nx8, pWt8, gel8, mWt8, (u8*)f1, projb);
  k_gemm_fin<<<dim3(8, 64), 256, 0, stream>>>((u8*)f1, W2t8, (float*)d_out, b2, x,
                                              ls_g);
}

// Round 8
// 224.323 us; speedup vs baseline: 1.0431x; 1.0187x over previous
//
#include <hip/hip_runtime.h>
#include <cstdint>
#include <cstddef>

typedef unsigned short u16;
typedef unsigned char u8;
typedef __attribute__((ext_vector_type(8))) u16 u16x8;
typedef __attribute__((ext_vector_type(8))) __bf16 bf16x8;
typedef __attribute__((ext_vector_type(4))) float f32x4;
typedef __attribute__((ext_vector_type(16))) float f32x16;
typedef __attribute__((ext_vector_type(4))) int i32x4;
typedef __attribute__((ext_vector_type(8))) int i32x8;
typedef __attribute__((ext_vector_type(2))) int i32x2;

__device__ __forceinline__ u16 f2bf(float f) {
  unsigned u = __builtin_bit_cast(unsigned, f);
  return (u16)((u + 0x7FFFu + ((u >> 16) & 1u)) >> 16);
}
__device__ __forceinline__ float bf2f(u16 h) {
  return __builtin_bit_cast(float, (unsigned)h << 16);
}
__device__ __forceinline__ u8 f2fp8(float f) {
  return (u8)(__builtin_amdgcn_cvt_pk_fp8_f32(f, 0.f, 0, false) & 0xFF);
}
__device__ __forceinline__ f32x16 mfma32(u16x8 a, u16x8 b, f32x16 c) {
  return __builtin_amdgcn_mfma_f32_32x32x16_bf16(
      __builtin_bit_cast(bf16x8, a), __builtin_bit_cast(bf16x8, b), c, 0, 0, 0);
}
__device__ __forceinline__ unsigned cvtpk_bf16(float lo, float hi) {
  unsigned r;
  asm("v_cvt_pk_bf16_f32 %0, %1, %2" : "=v"(r) : "v"(lo), "v"(hi));
  return r;
}
__device__ __forceinline__ float exp2_fast(float x) {
  float r;
  asm("v_exp_f32 %0, %1" : "=v"(r) : "v"(x));
  return r;
}
__device__ __forceinline__ void plswap(unsigned& a, unsigned& b) {
  i32x2 r = __builtin_amdgcn_permlane32_swap((int)a, (int)b, false, false);
  a = (unsigned)r[0];
  b = (unsigned)r[1];
}
__device__ __forceinline__ void load_lds16(const void* g, void* l) {
  __builtin_amdgcn_global_load_lds(
      (const __attribute__((address_space(1))) void*)g,
      (__attribute__((address_space(3))) void*)l, 16, 0, 0);
}

// ---------------- fused pre-pass: 4 weight transposes (fp8, K-TILED layout) +
// x LayerNorm (fp8). Tiled layout: dst[(panel*nkt + kt)*128 + (n&127)][k&63] --
// each GEMM K-step's B strip [128 rows x 64B] is one contiguous 8KB stream.
__global__ __launch_bounds__(256) void k_pre(
    const float* __restrict__ W1, const float* __restrict__ projW,
    const float* __restrict__ mlpW, const float* __restrict__ W2,
    u8* __restrict__ W1t, u8* __restrict__ pWt, u8* __restrict__ mWt,
    u8* __restrict__ W2t, const float* __restrict__ x,
    const float* __restrict__ g, const float* __restrict__ b,
    u8* __restrict__ nx8) {
  __shared__ float t[32][33];
  __shared__ float red[8];
  const int L = blockIdx.x;
  const int tid = threadIdx.x;
  if (L < 7680) {
    const float* src;
    u8* dst;
    int R, C, dR, dC, bx, by;
    if (L < 3840) {
      src = W1; dst = W1t; R = 1024; C = 3788; dR = 1024; dC = 3840;
      bx = L % 120; by = L / 120;
    } else if (L < 4864) {
      int tq = L - 3840;
      src = projW; dst = pWt; R = 1024; C = 1024; dR = 1024; dC = 1024;
      bx = tq & 31; by = tq >> 5;
    } else if (L < 5632) {
      int tq = L - 4864;
      src = mlpW; dst = mWt; R = 716; C = 1024; dR = 768; dC = 1024;
      bx = tq & 31; by = tq >> 5;
    } else {
      int tq = L - 5632;
      src = W2; dst = W2t; R = 2048; C = 1024; dR = 2048; dC = 1024;
      bx = tq & 31; by = tq >> 5;
    }
    const int n0 = bx * 32, k0 = by * 32;
    const int tx = tid & 31, ty = tid >> 5;
    const int nkt = dR >> 6;
#pragma unroll
    for (int j = 0; j < 4; ++j) {
      int kk = k0 + ty + 8 * j, nn = n0 + tx;
      float v = (kk < R && nn < C) ? src[(size_t)kk * C + nn] : 0.f;
      t[ty + 8 * j][tx] = v;
    }
    __syncthreads();
#pragma unroll
    for (int j = 0; j < 4; ++j) {
      int nn = n0 + ty + 8 * j, kk = k0 + tx;
      if (nn < dC && kk < dR) {
        const int p = nn >> 7, r = nn & 127, kt = kk >> 6, kb = kk & 63;
        dst[((size_t)(p * nkt + kt) * 128 + r) * 64 + kb] =
            f2fp8(t[tx][ty + 8 * j]);
      }
    }
  } else {
    const int row = L - 7680;
    float4 v = ((const float4*)(x + (size_t)row * 1024))[tid];
    float s = v.x + v.y + v.z + v.w;
    float ss = v.x * v.x + v.y * v.y + v.z * v.z + v.w * v.w;
#pragma unroll
    for (int off = 1; off < 64; off <<= 1) {
      s += __shfl_xor(s, off);
      ss += __shfl_xor(ss, off);
    }
    const int wid = tid >> 6, lane = tid & 63;
    if (lane == 0) { red[wid] = s; red[4 + wid] = ss; }
    __syncthreads();
    s = red[0] + red[1] + red[2] + red[3];
    ss = red[4] + red[5] + red[6] + red[7];
    const float mean = s * (1.f / 1024.f);
    const float var = ss * (1.f / 1024.f) - mean * mean;
    const float rstd = rsqrtf(var + 1e-5f);
    float4 gv = ((const float4*)g)[tid];
    float4 bv = ((const float4*)b)[tid];
    float y0 = (v.x - mean) * rstd * gv.x + bv.x;
    float y1 = (v.y - mean) * rstd * gv.y + bv.y;
    float y2 = (v.z - mean) * rstd * gv.z + bv.z;
    float y3 = (v.w - mean) * rstd * gv.w + bv.w;
    int pk = __builtin_amdgcn_cvt_pk_fp8_f32(y0, y1, 0, false);
    pk = __builtin_amdgcn_cvt_pk_fp8_f32(y2, y3, pk, true);
    ((int*)(nx8 + (size_t)row * 1024))[tid] = pk;
  }
}

// ---------------- MX-fp8 GEMM core 128x128, 3-deep pipeline, counted vmcnt,
// ONE barrier per K-step (round-4 empirical best). B is K-TILED:
// B + kt*8192 + row*64 (contiguous 8KB stream per K-step).
__device__ __forceinline__ void gemm_fp8_core(const u8* __restrict__ A,
                                              const u8* __restrict__ B, int K,
                                              u8* Alds, u8* Blds,
                                              f32x16 (&acc)[2][2], int tid) {
  const int lane = tid & 63, wave = tid >> 6;
  const int h = lane >> 5, r32 = lane & 31;
  const int wrow = (wave >> 1) * 64, wcol = (wave & 1) * 64;
  const int srow0 = tid >> 2, spos = tid & 3;
  const int nk = K >> 6;
  auto STAGE = [&](int t, int bb) {
#pragma unroll
    for (int p = 0; p < 2; ++p) {
      const int row = p * 64 + srow0;
      const int c = spos ^ ((row >> 1) & 3);
      load_lds16(A + (size_t)row * K + (size_t)t * 64 + c * 16,
                 Alds + bb * 8192 + (p * 256 + tid) * 16);
      load_lds16(B + (size_t)t * 8192 + row * 64 + c * 16,
                 Blds + bb * 8192 + (p * 256 + tid) * 16);
    }
  };
  STAGE(0, 0);
  STAGE(1, 1);
  asm volatile("s_waitcnt vmcnt(4)" ::: "memory");
  __builtin_amdgcn_s_barrier();
  int cur = 0;
  for (int kt = 0; kt < nk; ++kt) {
    const u8* Ac = Alds + cur * 8192;
    const u8* Bc = Blds + cur * 8192;
    i32x8 af[2], bf[2];
#pragma unroll
    for (int t = 0; t < 2; ++t) {
      {
        const int row = wrow + t * 32 + r32;
        const int sw = (row >> 1) & 3;
        i32x4 lo = *(const i32x4*)(Ac + row * 64 + ((2 * h) ^ sw) * 16);
        i32x4 hi = *(const i32x4*)(Ac + row * 64 + ((2 * h + 1) ^ sw) * 16);
        i32x8 a;
        a[0] = lo[0]; a[1] = lo[1]; a[2] = lo[2]; a[3] = lo[3];
        a[4] = hi[0]; a[5] = hi[1]; a[6] = hi[2]; a[7] = hi[3];
        af[t] = a;
      }
      {
        const int row = wcol + t * 32 + r32;
        const int sw = (row >> 1) & 3;
        i32x4 lo = *(const i32x4*)(Bc + row * 64 + ((2 * h) ^ sw) * 16);
        i32x4 hi = *(const i32x4*)(Bc + row * 64 + ((2 * h + 1) ^ sw) * 16);
        i32x8 b8;
        b8[0] = lo[0]; b8[1] = lo[1]; b8[2] = lo[2]; b8[3] = lo[3];
        b8[4] = hi[0]; b8[5] = hi[1]; b8[6] = hi[2]; b8[7] = hi[3];
        bf[t] = b8;
      }
    }
    if (kt + 2 < nk) STAGE(kt + 2, cur == 0 ? 2 : cur - 1);
#pragma unroll
    for (int i = 0; i < 2; ++i)
#pragma unroll
      for (int j = 0; j < 2; ++j)
        acc[i][j] = __builtin_amdgcn_mfma_scale_f32_32x32x64_f8f6f4(
            af[i], bf[j], acc[i][j], 0, 0, 0, 0x7F7F7F7F, 0, 0x7F7F7F7F);
    if (kt + 1 < nk) {
      if (kt + 2 < nk)
        asm volatile("s_waitcnt vmcnt(4)" ::: "memory");
      else
        asm volatile("s_waitcnt vmcnt(0)" ::: "memory");
      __builtin_amdgcn_s_barrier();
    }
    cur = (cur == 2) ? 0 : cur + 1;
  }
}

// ---------------- MX-fp8 GEMM core 64(M)x128(N), 3-deep, counted vmcnt, tiled B
__device__ __forceinline__ void gemm_fp8_core64(const u8* __restrict__ A,
                                                const u8* __restrict__ B, int K,
                                                u8* Alds, u8* Blds,
                                                f32x16 (&acc)[2], int tid) {
  const int lane = tid & 63, wave = tid >> 6;
  const int h = lane >> 5, r32 = lane & 31;
  const int wrow = (wave >> 1) * 32, wcol = (wave & 1) * 64;
  const int nk = K >> 6;
  const int ra = tid >> 2, posa = tid & 3;
  const int ca = posa ^ ((ra >> 1) & 3);
  auto STAGE = [&](int t, int bb) {
    load_lds16(A + (size_t)ra * K + (size_t)t * 64 + ca * 16,
               Alds + bb * 4096 + tid * 16);
#pragma unroll
    for (int p = 0; p < 2; ++p) {
      const int s = tid + 256 * p;
      const int r = s >> 2, pos = s & 3;
      const int c = pos ^ ((r >> 1) & 3);
      load_lds16(B + (size_t)t * 8192 + r * 64 + c * 16, Blds + bb * 8192 + s * 16);
    }
  };
  STAGE(0, 0);
  STAGE(1, 1);
  asm volatile("s_waitcnt vmcnt(3)" ::: "memory");
  __builtin_amdgcn_s_barrier();
  int cur = 0;
  for (int kt = 0; kt < nk; ++kt) {
    const u8* Ac = Alds + cur * 4096;
    const u8* Bc = Blds + cur * 8192;
    i32x8 af, bf[2];
    {
      const int row = wrow + r32;
      const int sw = (row >> 1) & 3;
      i32x4 lo = *(const i32x4*)(Ac + row * 64 + ((2 * h) ^ sw) * 16);
      i32x4 hi = *(const i32x4*)(Ac + row * 64 + ((2 * h + 1) ^ sw) * 16);
      af[0] = lo[0]; af[1] = lo[1]; af[2] = lo[2]; af[3] = lo[3];
      af[4] = hi[0]; af[5] = hi[1]; af[6] = hi[2]; af[7] = hi[3];
    }
#pragma unroll
    for (int t = 0; t < 2; ++t) {
      const int row = wcol + t * 32 + r32;
      const int sw = (row >> 1) & 3;
      i32x4 lo = *(const i32x4*)(Bc + row * 64 + ((2 * h) ^ sw) * 16);
      i32x4 hi = *(const i32x4*)(Bc + row * 64 + ((2 * h + 1) ^ sw) * 16);
      i32x8 b8;
      b8[0] = lo[0]; b8[1] = lo[1]; b8[2] = lo[2]; b8[3] = lo[3];
      b8[4] = hi[0]; b8[5] = hi[1]; b8[6] = hi[2]; b8[7] = hi[3];
      bf[t] = b8;
    }
    if (kt + 2 < nk) STAGE(kt + 2, cur == 0 ? 2 : cur - 1);
#pragma unroll
    for (int j = 0; j < 2; ++j)
      acc[j] = __builtin_amdgcn_mfma_scale_f32_32x32x64_f8f6f4(
          af, bf[j], acc[j], 0, 0, 0, 0x7F7F7F7F, 0, 0x7F7F7F7F);
    if (kt + 1 < nk) {
      if (kt + 2 < nk)
        asm volatile("s_waitcnt vmcnt(3)" ::: "memory");
      else
        asm volatile("s_waitcnt vmcnt(0)" ::: "memory");
      __builtin_amdgcn_s_barrier();
    }
    cur = (cur == 2) ? 0 : cur + 1;
  }
}

// ---------------- GEMM1 + fused epilogue, XCD-chunked 1D grid (960 blocks).
// chunk c = L&7 (lands on XCD c): bm in [(c&3)*8, +8), bn in [(c>>2)*15, +15)
// -> per-XCD working set A 1MB + B 1.9MB < 4MB L2 (kills W1t x8 replication).
__global__ __launch_bounds__(256) void k_gemm1(
    const u8* __restrict__ nx8, const u8* __restrict__ W1t, u16* __restrict__ f1,
    const float* __restrict__ b1, const float* __restrict__ qg,
    const float* __restrict__ qb_, const float* __restrict__ kg,
    const float* __restrict__ kb_, u16* __restrict__ qbuf, u16* __restrict__ kbuf,
    u8* __restrict__ gel8) {
  __shared__ __align__(16) u8 Alds[3 * 128 * 64];
  __shared__ __align__(16) u8 Blds[3 * 128 * 64];
  const int tid = threadIdx.x;
  const int L = blockIdx.x;
  const int c = L & 7, inner = L >> 3;           // inner 0..119
  const int bm = (c & 3) * 8 + (inner & 7);
  const int bn = (c >> 2) * 15 + (inner >> 3);   // inner>>3 in 0..14
  f32x16 acc[2][2];
#pragma unroll
  for (int i = 0; i < 2; ++i)
#pragma unroll
    for (int j = 0; j < 2; ++j)
#pragma unroll
      for (int r = 0; r < 16; ++r) acc[i][j][r] = 0.f;
  gemm_fp8_core(nx8 + (size_t)bm * 128 * 1024, W1t + (size_t)bn * 128 * 1024, 1024,
                Alds, Blds, acc, tid);
  const int lane = tid & 63, wave = tid >> 6;
  const int h = lane >> 5, r32 = lane & 31;
  const int wrow = (wave >> 1) * 64, wcol = (wave & 1) * 64;
  if (bn < 16) {
    const int wc = bn * 128 + wcol;     // multiple of 64, < 2048
    const int which = wc >> 10;         // 0 = q, 1 = k
    const int head = (wc >> 6) & 15;
    const float* g = which ? kg : qg;
    const float* bb = which ? kb_ : qb_;
    const float g0 = g[r32], g1 = g[32 + r32];
    const float be0 = bb[r32], be1 = bb[32 + r32];
    const float bias0 = b1[wc + r32], bias1 = b1[wc + 32 + r32];
    u16* dst = which ? kbuf : qbuf;
#pragma unroll
    for (int i = 0; i < 2; ++i)
#pragma unroll
      for (int r = 0; r < 16; ++r) {
        float v0 = acc[i][0][r] + bias0;
        float v1 = acc[i][1][r] + bias1;
        float s = v0 + v1, ss = v0 * v0 + v1 * v1;
#pragma unroll
        for (int off = 1; off < 32; off <<= 1) {
          s += __shfl_xor(s, off);
          ss += __shfl_xor(ss, off);
        }
        const float mean = s * (1.f / 64.f);
        const float var = ss * (1.f / 64.f) - mean * mean;
        const float rstd = rsqrtf(var + 1e-5f);
        const int row = bm * 128 + wrow + i * 32 + 4 * h + (r & 3) + 8 * (r >> 2);
        const int b = row >> 10, n = row & 1023;
        u16* orow = dst + ((size_t)(b * 16 + head) * 1024 + n) * 64;
        orow[r32] = f2bf((v0 - mean) * rstd * g0 + be0);
        orow[32 + r32] = f2bf((v1 - mean) * rstd * g1 + be1);
      }
  } else if (bn < 24) {
#pragma unroll
    for (int i = 0; i < 2; ++i)
#pragma unroll
      for (int j = 0; j < 2; ++j) {
        const int col = bn * 128 + wcol + j * 32 + r32;
        const float bs = b1[col];
#pragma unroll
        for (int r = 0; r < 16; ++r) {
          const int row = bm * 128 + wrow + i * 32 + 4 * h + (r & 3) + 8 * (r >> 2);
          f1[(size_t)row * 3840 + col] = f2bf(acc[i][j][r] + bs);
        }
      }
  } else {
#pragma unroll
    for (int i = 0; i < 2; ++i)
#pragma unroll
      for (int j = 0; j < 2; ++j) {
        const int col = bn * 128 + wcol + j * 32 + r32;
        const int cc = col - 3072;
        const bool ok = (col < 3788);
        const float bs = ok ? b1[col] : 0.f;
#pragma unroll
        for (int r = 0; r < 16; ++r) {
          const int row = bm * 128 + wrow + i * 32 + 4 * h + (r & 3) + 8 * (r >> 2);
          float y = acc[i][j][r] + bs;
          float ge = ok ? 0.5f * y * (1.f + erff(y * 0.70710678118654752f)) : 0.f;
          gel8[(size_t)row * 768 + cc] = f2fp8(ge);
        }
      }
  }
}

// ---------------- proj + mlp fused (64-row tiles): comb[4096][2048] fp8
__global__ __launch_bounds__(256) void k_gemm_pm(
    const u8* __restrict__ xo, const u8* __restrict__ pWt,
    const u8* __restrict__ gel, const u8* __restrict__ mWt,
    u8* __restrict__ comb, const float* __restrict__ projb) {
  __shared__ __align__(16) u8 Alds[3 * 64 * 64];
  __shared__ __align__(16) u8 Blds[3 * 128 * 64];
  const int tid = threadIdx.x, bm = blockIdx.y, bnq = blockIdx.x;
  const u8* A;
  const u8* B;
  int K, colbase;
  const float* bias;
  if (bnq < 8) {
    A = xo + (size_t)bm * 64 * 1024;
    B = pWt + (size_t)bnq * 128 * 1024;
    K = 1024; colbase = bnq * 128; bias = projb;
  } else {
    A = gel + (size_t)bm * 64 * 768;
    B = mWt + (size_t)(bnq - 8) * 128 * 768;
    K = 768; colbase = 1024 + (bnq - 8) * 128; bias = nullptr;
  }
  f32x16 acc[2];
#pragma unroll
  for (int j = 0; j < 2; ++j)
#pragma unroll
    for (int r = 0; r < 16; ++r) acc[j][r] = 0.f;
  gemm_fp8_core64(A, B, K, Alds, Blds, acc, tid);
  const int lane = tid & 63, wave = tid >> 6;
  const int h = lane >> 5, r32 = lane & 31;
  const int wrow = (wave >> 1) * 32, wcol = (wave & 1) * 64;
#pragma unroll
  for (int j = 0; j < 2; ++j) {
    const int col = colbase + wcol + j * 32 + r32;
    const float bs = (bias != nullptr) ? bias[col] : 0.f;
#pragma unroll
    for (int r = 0; r < 16; ++r) {
      const int row = bm * 64 + wrow + 4 * h + (r & 3) + 8 * (r >> 2);
      comb[(size_t)row * 2048 + col] = f2fp8(acc[j][r] + bs);
    }
  }
}

// ---------------- final (64-row tiles): out = x + (comb @ W2t^T + b2) * ls_g
__global__ __launch_bounds__(256) void k_gemm_fin(const u8* __restrict__ comb,
                                                  const u8* __restrict__ W2t,
                                                  float* __restrict__ out,
                                                  const float* __restrict__ b2,
                                                  const float* __restrict__ x,
                                                  const float* __restrict__ lsg) {
  __shared__ __align__(16) u8 Alds[3 * 64 * 64];
  __shared__ __align__(16) u8 Blds[3 * 128 * 64];
  const int tid = threadIdx.x, bm = blockIdx.y, bn = blockIdx.x;
  f32x16 acc[2];
#pragma unroll
  for (int j = 0; j < 2; ++j)
#pragma unroll
    for (int r = 0; r < 16; ++r) acc[j][r] = 0.f;
  gemm_fp8_core64(comb + (size_t)bm * 64 * 2048, W2t + (size_t)bn * 128 * 2048, 2048,
                  Alds, Blds, acc, tid);
  const int lane = tid & 63, wave = tid >> 6;
  const int h = lane >> 5, r32 = lane & 31;
  const int wrow = (wave >> 1) * 32, wcol = (wave & 1) * 64;
#pragma unroll
  for (int j = 0; j < 2; ++j) {
    const int col = bn * 128 + wcol + j * 32 + r32;
    const float bs = b2[col], ls = lsg[col];
#pragma unroll
    for (int r = 0; r < 16; ++r) {
      const int row = bm * 64 + wrow + 4 * h + (r & 3) + 8 * (r >> 2);
      out[(size_t)row * 1024 + col] =
          x[(size_t)row * 1024 + col] + (acc[j][r] + bs) * ls;
    }
  }
}

// ---------------- V^T extraction: vtb[bh][d][n]
__global__ __launch_bounds__(256) void k_mid(const u16* __restrict__ f1,
                                             u16* __restrict__ vtb) {
  __shared__ u16 tt[32][33];
  const int tid = threadIdx.x;
  const int t = blockIdx.x;  // [0, 4096)
  const int xq = t & 1, yq = (t >> 1) & 31, z = t >> 6;
  const int b = z >> 4, h = z & 15;
  const int d0 = xq * 32, n0 = yq * 32;
  const int tx = tid & 31, ty = tid >> 5;
#pragma unroll
  for (int j = 0; j < 4; ++j)
    tt[ty + 8 * j][tx] =
        f1[(size_t)(b * 1024 + n0 + ty + 8 * j) * 3840 + 2048 + h * 64 + d0 + tx];
  __syncthreads();
#pragma unroll
  for (int j = 0; j < 4; ++j)
    vtb[(size_t)z * 65536 + (size_t)(d0 + ty + 8 * j) * 1024 + n0 + tx] =
        tt[tx][ty + 8 * j];
}

// ---------------- flash attention v6: zero-barrier 1-wave blocks + T15 two-tile
// pipeline (QK(t+1) before softmax/PV(t)); counted vmcnt (T4); in-register P
// (cvt_pk + permlane32_swap, T12). 16KB LDS, grid 2048 x 64thr.
__global__ __launch_bounds__(64) void k_flash(const u16* __restrict__ q,
                                              const u16* __restrict__ k,
                                              const u16* __restrict__ vt,
                                              u8* __restrict__ xo) {
  __shared__ __align__(16) u16 Kl[2][32 * 64];
  __shared__ __align__(16) u16 Vl[2][64 * 32];
  const int lane = threadIdx.x & 63;
  const int l31 = lane & 31, h = lane >> 5;
  const int L = blockIdx.x;
  const int xcd = L & 7, i = L >> 3;
  const int bh = xcd * 8 + (i & 7);
  const int qt = i >> 3;
  const int qrow0 = qt * 32;
  const u16* qb = q + ((size_t)bh * 1024 + qrow0) * 64;
  const u16* kb = k + (size_t)bh * 1024 * 64;
  const u16* vb = vt + (size_t)bh * 64 * 1024;

  u16x8 qf[4];
#pragma unroll
  for (int ds = 0; ds < 4; ++ds)
    qf[ds] = *(const u16x8*)(qb + (size_t)l31 * 64 + ds * 16 + h * 8);
  asm volatile("s_waitcnt vmcnt(0)" ::: "memory");

  f32x16 O[2];
#pragma unroll
  for (int d2 = 0; d2 < 2; ++d2)
#pragma unroll
    for (int r = 0; r < 16; ++r) O[d2][r] = 0.f;
  float lacc = 0.f;

  auto STAGE = [&](int t, int bb) {
#pragma unroll
    for (int p = 0; p < 4; ++p) {
      const int s = lane + 64 * p;
      const int kr = s >> 3, kslot = s & 7;
      const int kc = kslot ^ ((kr ^ (kr >> 3)) & 7);
      load_lds16(kb + (size_t)(t * 32 + kr) * 64 + kc * 8, (u16*)Kl[bb] + s * 8);
      const int vr = s >> 2, vslot = s & 3;
      const int vc = vslot ^ ((vr >> 1) & 3);
      load_lds16(vb + (size_t)vr * 1024 + t * 32 + vc * 8, (u16*)Vl[bb] + s * 8);
    }
  };
  STAGE(0, 0);
  STAGE(1, 1);

  const int swzk = (l31 & 7) ^ ((l31 >> 3) & 3);
  const float C = 0.18033688011112042f;  // 0.125 * log2(e)

  f32x16 Sa, Sb;
  u16x8 vfA[4], vfB[4];

  auto READ_FRAGS = [&](int t, u16x8 (&kf)[4], u16x8 (&vf)[4]) {
    const u16* Kc = (const u16*)Kl[t & 1];
    const u16* Vc = (const u16*)Vl[t & 1];
#pragma unroll
    for (int ds = 0; ds < 4; ++ds)
      kf[ds] = *(const u16x8*)(Kc + l31 * 64 + (((ds * 2 + h) ^ swzk)) * 8);
#pragma unroll
    for (int m = 0; m < 2; ++m)
#pragma unroll
      for (int d2 = 0; d2 < 2; ++d2) {
        const int vr = d2 * 32 + l31;
        const int pos = (m * 2 + h) ^ ((vr >> 1) & 3);
        vf[m * 2 + d2] = *(const u16x8*)(Vc + vr * 32 + pos * 8);
      }
  };

  // prologue: tile 0 -> Sa, vfA
  {
    asm volatile("s_waitcnt vmcnt(8)" ::: "memory");
    u16x8 kf[4];
    READ_FRAGS(0, kf, vfA);
    asm volatile("s_waitcnt lgkmcnt(0)" ::: "memory");
    __builtin_amdgcn_sched_barrier(0);
    STAGE(2, 0);
#pragma unroll
    for (int r = 0; r < 16; ++r) Sa[r] = 0.f;
    __builtin_amdgcn_s_setprio(1);
#pragma unroll
    for (int ds = 0; ds < 4; ++ds) Sa = mfma32(kf[ds], qf[ds], Sa);
    __builtin_amdgcn_s_setprio(0);
  }

  auto TILE = [&](int t, f32x16& Sc, f32x16& Sn, u16x8 (&vc)[4], u16x8 (&vn)[4]) {
    if (t < 31) {
      if (t <= 29)
        asm volatile("s_waitcnt vmcnt(8)" ::: "memory");
      else
        asm volatile("s_waitcnt vmcnt(0)" ::: "memory");
      u16x8 kf[4];
      READ_FRAGS(t + 1, kf, vn);
      asm volatile("s_waitcnt lgkmcnt(0)" ::: "memory");
      __builtin_amdgcn_sched_barrier(0);
      if (t + 3 < 32) STAGE(t + 3, (t + 3) & 1);
#pragma unroll
      for (int r = 0; r < 16; ++r) Sn[r] = 0.f;
      __builtin_amdgcn_s_setprio(1);
#pragma unroll
      for (int ds = 0; ds < 4; ++ds) Sn = mfma32(kf[ds], qf[ds], Sn);
      __builtin_amdgcn_s_setprio(0);
    }
#pragma unroll
    for (int r = 0; r < 16; ++r) {
      float pv = exp2_fast(Sc[r] * C);
      Sc[r] = pv;
      lacc += pv;
    }
    __builtin_amdgcn_s_setprio(1);
#pragma unroll
    for (int m = 0; m < 2; ++m) {
      const int ro = m * 8;
      unsigned w0 = cvtpk_bf16(Sc[ro + 0], Sc[ro + 1]);
      unsigned w2 = cvtpk_bf16(Sc[ro + 4], Sc[ro + 5]);
      unsigned w1 = cvtpk_bf16(Sc[ro + 2], Sc[ro + 3]);
      unsigned w3 = cvtpk_bf16(Sc[ro + 6], Sc[ro + 7]);
      plswap(w0, w2);
      plswap(w1, w3);
      i32x4 aw;
      aw[0] = (int)w0; aw[1] = (int)w1; aw[2] = (int)w2; aw[3] = (int)w3;
      const u16x8 pa = __builtin_bit_cast(u16x8, aw);
#pragma unroll
      for (int d2 = 0; d2 < 2; ++d2) O[d2] = mfma32(pa, vc[m * 2 + d2], O[d2]);
    }
    __builtin_amdgcn_s_setprio(0);
  };

  for (int t = 0; t < 32; t += 2) {
    TILE(t, Sa, Sb, vfA, vfB);
    TILE(t + 1, Sb, Sa, vfB, vfA);
  }

  lacc += __shfl_xor(lacc, 32);
  const float inv = 1.f / lacc;
  const int b = bh >> 4, hh = bh & 15;
#pragma unroll
  for (int r = 0; r < 16; ++r) {
    const int qr = (r & 3) + 8 * (r >> 2) + 4 * h;
    const float invr = __shfl(inv, qr);
    u8* orow = xo + (size_t)(b * 1024 + qrow0 + qr) * 1024 + hh * 64;
    orow[l31] = f2fp8(O[0][r] * invr);
    orow[32 + l31] = f2fp8(O[1][r] * invr);
  }
}

extern "C" void kernel_launch(void* const* d_in, const int* in_sizes, int n_in,
                              void* d_out, int out_size, void* d_ws, size_t ws_size,
                              hipStream_t stream) {
  (void)in_sizes; (void)n_in; (void)out_size; (void)ws_size;
  const float* x      = (const float*)d_in[0];
  const float* norm_g = (const float*)d_in[1];
  const float* norm_b = (const float*)d_in[2];
  const float* W1     = (const float*)d_in[3];
  const float* b1     = (const float*)d_in[4];
  const float* qn_g   = (const float*)d_in[5];
  const float* qn_b   = (const float*)d_in[6];
  const float* kn_g   = (const float*)d_in[7];
  const float* kn_b   = (const float*)d_in[8];
  const float* projW  = (const float*)d_in[9];
  const float* projb  = (const float*)d_in[10];
  const float* mlpW   = (const float*)d_in[11];
  const float* W2     = (const float*)d_in[12];
  const float* b2     = (const float*)d_in[13];
  const float* ls_g   = (const float*)d_in[14];

  char* ws = (char*)d_ws;
  u8*  W1t8 = (u8*)(ws + 0);           // [3840][1024]  3,932,160 (K-tiled)
  u8*  pWt8 = (u8*)(ws + 3932160);     // [1024][1024]  1,048,576 (K-tiled)
  u8*  mWt8 = (u8*)(ws + 4980736);     // [1024][768]     786,432 (K-tiled)
  u8*  W2t8 = (u8*)(ws + 5767168);     // [1024][2048]  2,097,152 (K-tiled)
  u8*  nx8  = (u8*)(ws + 7864320);     // [4096][1024]  4,194,304 (then xo8)
  u16* f1   = (u16*)(ws + 12058624);   // [4096][3840] bf16 (V region; then comb fp8)
  u16* qbuf = (u16*)(ws + 43515904);   // [64][1024][64] 8,388,608
  u16* kbuf = (u16*)(ws + 51904512);   // [64][1024][64] 8,388,608
  u16* vtb  = (u16*)(ws + 60293120);   // [64][64][1024] 8,388,608
  u8*  gel8 = (u8*)(ws + 68681728);    // [4096][768]   3,145,728

  k_pre<<<11776, 256, 0, stream>>>(W1, projW, mlpW, W2, W1t8, pWt8, mWt8, W2t8,
                                   x, norm_g, norm_b, nx8);
  k_gemm1<<<960, 256, 0, stream>>>(nx8, W1t8, f1, b1, qn_g, qn_b, kn_g, kn_b,
                                   qbuf, kbuf, gel8);
  k_mid<<<4096, 256, 0, stream>>>(f1, vtb);
  k_flash<<<2048, 64, 0, stream>>>(qbuf, kbuf, vtb, nx8);
  k_gemm_pm<<<dim3(16, 64), 256, 0, stream>>>(nx8, pWt8, gel8, mWt8, (u8*)f1, projb);
  k_gemm_fin<<<dim3(8, 64), 256, 0, stream>>>((u8*)f1, W2t8, (float*)d_out, b2, x,
                                              ls_g);
}

// Round 9
// 223.989 us; speedup vs baseline: 1.0447x; 1.0015x over previous
//
#include <hip/hip_runtime.h>
#include <cstdint>
#include <cstddef>

typedef unsigned short u16;
typedef unsigned char u8;
typedef __attribute__((ext_vector_type(8))) u16 u16x8;
typedef __attribute__((ext_vector_type(8))) __bf16 bf16x8;
typedef __attribute__((ext_vector_type(4))) float f32x4;
typedef __attribute__((ext_vector_type(16))) float f32x16;
typedef __attribute__((ext_vector_type(4))) int i32x4;
typedef __attribute__((ext_vector_type(8))) int i32x8;
typedef __attribute__((ext_vector_type(2))) int i32x2;

__device__ __forceinline__ u16 f2bf(float f) {
  unsigned u = __builtin_bit_cast(unsigned, f);
  return (u16)((u + 0x7FFFu + ((u >> 16) & 1u)) >> 16);
}
__device__ __forceinline__ float bf2f(u16 h) {
  return __builtin_bit_cast(float, (unsigned)h << 16);
}
__device__ __forceinline__ u8 f2fp8(float f) {
  return (u8)(__builtin_amdgcn_cvt_pk_fp8_f32(f, 0.f, 0, false) & 0xFF);
}
__device__ __forceinline__ f32x16 mfma32(u16x8 a, u16x8 b, f32x16 c) {
  return __builtin_amdgcn_mfma_f32_32x32x16_bf16(
      __builtin_bit_cast(bf16x8, a), __builtin_bit_cast(bf16x8, b), c, 0, 0, 0);
}
__device__ __forceinline__ unsigned cvtpk_bf16(float lo, float hi) {
  unsigned r;
  asm("v_cvt_pk_bf16_f32 %0, %1, %2" : "=v"(r) : "v"(lo), "v"(hi));
  return r;
}
__device__ __forceinline__ float exp2_fast(float x) {
  float r;
  asm("v_exp_f32 %0, %1" : "=v"(r) : "v"(x));
  return r;
}
__device__ __forceinline__ void plswap(unsigned& a, unsigned& b) {
  i32x2 r = __builtin_amdgcn_permlane32_swap((int)a, (int)b, false, false);
  a = (unsigned)r[0];
  b = (unsigned)r[1];
}
__device__ __forceinline__ void load_lds16(const void* g, void* l) {
  __builtin_amdgcn_global_load_lds(
      (const __attribute__((address_space(1))) void*)g,
      (__attribute__((address_space(3))) void*)l, 16, 0, 0);
}

// ---------------- fused pre-pass v2: 64x64 transpose tiles (fp8 K-tiled, fully
// coalesced: 256B-row reads, one 16B i32x4 store/thread into a 4KB stream) +
// x LayerNorm. L < 1920: tiles (W1 960, proj 256, mlp 192, W2 512); else LN rows.
__global__ __launch_bounds__(256) void k_pre(
    const float* __restrict__ W1, const float* __restrict__ projW,
    const float* __restrict__ mlpW, const float* __restrict__ W2,
    u8* __restrict__ W1t, u8* __restrict__ pWt, u8* __restrict__ mWt,
    u8* __restrict__ W2t, const float* __restrict__ x,
    const float* __restrict__ g, const float* __restrict__ b,
    u8* __restrict__ nx8) {
  __shared__ float tt[64][65];
  __shared__ float red[8];
  const int L = blockIdx.x;
  const int tid = threadIdx.x;
  if (L < 1920) {
    const float* src;
    u8* dst;
    int R, C, nkt, bx, by;
    if (L < 960) {
      src = W1; dst = W1t; R = 1024; C = 3788; nkt = 16; bx = L / 16; by = L % 16;
    } else if (L < 1216) {
      int t = L - 960;
      src = projW; dst = pWt; R = 1024; C = 1024; nkt = 16; bx = t / 16; by = t % 16;
    } else if (L < 1408) {
      int t = L - 1216;
      src = mlpW; dst = mWt; R = 716; C = 1024; nkt = 12; bx = t / 12; by = t % 12;
    } else {
      int t = L - 1408;
      src = W2; dst = W2t; R = 2048; C = 1024; nkt = 32; bx = t / 32; by = t % 32;
    }
    const int n0 = bx * 64, k0 = by * 64;
    const int lr = tid >> 6, lc = tid & 63;
#pragma unroll
    for (int j = 0; j < 16; ++j) {
      const int kk = k0 + lr + 4 * j, nn = n0 + lc;
      tt[lr + 4 * j][lc] = (kk < R && nn < C) ? src[(size_t)kk * C + nn] : 0.f;
    }
    __syncthreads();
    const int rn = tid >> 2;        // local n row 0..63
    const int kb = (tid & 3) * 16;  // k-byte offset 0,16,32,48
    i32x4 st;
#pragma unroll
    for (int w = 0; w < 4; ++w) {
      int p0 = __builtin_amdgcn_cvt_pk_fp8_f32(tt[kb + 4 * w + 0][rn],
                                               tt[kb + 4 * w + 1][rn], 0, false);
      p0 = __builtin_amdgcn_cvt_pk_fp8_f32(tt[kb + 4 * w + 2][rn],
                                           tt[kb + 4 * w + 3][rn], p0, true);
      st[w] = p0;
    }
    const int nn_g = n0 + rn;
    const int p = nn_g >> 7, rr = nn_g & 127;
    *(i32x4*)(dst + ((size_t)(p * nkt + by) * 128 + rr) * 64 + kb) = st;
  } else {
    const int row = L - 1920;
    float4 v = ((const float4*)(x + (size_t)row * 1024))[tid];
    float s = v.x + v.y + v.z + v.w;
    float ss = v.x * v.x + v.y * v.y + v.z * v.z + v.w * v.w;
#pragma unroll
    for (int off = 1; off < 64; off <<= 1) {
      s += __shfl_xor(s, off);
      ss += __shfl_xor(ss, off);
    }
    const int wid = tid >> 6, lane = tid & 63;
    if (lane == 0) { red[wid] = s; red[4 + wid] = ss; }
    __syncthreads();
    s = red[0] + red[1] + red[2] + red[3];
    ss = red[4] + red[5] + red[6] + red[7];
    const float mean = s * (1.f / 1024.f);
    const float var = ss * (1.f / 1024.f) - mean * mean;
    const float rstd = rsqrtf(var + 1e-5f);
    float4 gv = ((const float4*)g)[tid];
    float4 bv = ((const float4*)b)[tid];
    float y0 = (v.x - mean) * rstd * gv.x + bv.x;
    float y1 = (v.y - mean) * rstd * gv.y + bv.y;
    float y2 = (v.z - mean) * rstd * gv.z + bv.z;
    float y3 = (v.w - mean) * rstd * gv.w + bv.w;
    int pk = __builtin_amdgcn_cvt_pk_fp8_f32(y0, y1, 0, false);
    pk = __builtin_amdgcn_cvt_pk_fp8_f32(y2, y3, pk, true);
    ((int*)(nx8 + (size_t)row * 1024))[tid] = pk;
  }
}

// ---------------- MX-fp8 GEMM core 128x128, 3-deep pipeline, counted vmcnt,
// ONE barrier per K-step. B is K-TILED: B + kt*8192 + row*64 (contiguous 8KB).
__device__ __forceinline__ void gemm_fp8_core(const u8* __restrict__ A,
                                              const u8* __restrict__ B, int K,
                                              u8* Alds, u8* Blds,
                                              f32x16 (&acc)[2][2], int tid) {
  const int lane = tid & 63, wave = tid >> 6;
  const int h = lane >> 5, r32 = lane & 31;
  const int wrow = (wave >> 1) * 64, wcol = (wave & 1) * 64;
  const int srow0 = tid >> 2, spos = tid & 3;
  const int nk = K >> 6;
  auto STAGE = [&](int t, int bb) {
#pragma unroll
    for (int p = 0; p < 2; ++p) {
      const int row = p * 64 + srow0;
      const int c = spos ^ ((row >> 1) & 3);
      load_lds16(A + (size_t)row * K + (size_t)t * 64 + c * 16,
                 Alds + bb * 8192 + (p * 256 + tid) * 16);
      load_lds16(B + (size_t)t * 8192 + row * 64 + c * 16,
                 Blds + bb * 8192 + (p * 256 + tid) * 16);
    }
  };
  STAGE(0, 0);
  STAGE(1, 1);
  asm volatile("s_waitcnt vmcnt(4)" ::: "memory");
  __builtin_amdgcn_s_barrier();
  int cur = 0;
  for (int kt = 0; kt < nk; ++kt) {
    const u8* Ac = Alds + cur * 8192;
    const u8* Bc = Blds + cur * 8192;
    i32x8 af[2], bf[2];
#pragma unroll
    for (int t = 0; t < 2; ++t) {
      {
        const int row = wrow + t * 32 + r32;
        const int sw = (row >> 1) & 3;
        i32x4 lo = *(const i32x4*)(Ac + row * 64 + ((2 * h) ^ sw) * 16);
        i32x4 hi = *(const i32x4*)(Ac + row * 64 + ((2 * h + 1) ^ sw) * 16);
        i32x8 a;
        a[0] = lo[0]; a[1] = lo[1]; a[2] = lo[2]; a[3] = lo[3];
        a[4] = hi[0]; a[5] = hi[1]; a[6] = hi[2]; a[7] = hi[3];
        af[t] = a;
      }
      {
        const int row = wcol + t * 32 + r32;
        const int sw = (row >> 1) & 3;
        i32x4 lo = *(const i32x4*)(Bc + row * 64 + ((2 * h) ^ sw) * 16);
        i32x4 hi = *(const i32x4*)(Bc + row * 64 + ((2 * h + 1) ^ sw) * 16);
        i32x8 b8;
        b8[0] = lo[0]; b8[1] = lo[1]; b8[2] = lo[2]; b8[3] = lo[3];
        b8[4] = hi[0]; b8[5] = hi[1]; b8[6] = hi[2]; b8[7] = hi[3];
        bf[t] = b8;
      }
    }
    if (kt + 2 < nk) STAGE(kt + 2, cur == 0 ? 2 : cur - 1);
#pragma unroll
    for (int i = 0; i < 2; ++i)
#pragma unroll
      for (int j = 0; j < 2; ++j)
        acc[i][j] = __builtin_amdgcn_mfma_scale_f32_32x32x64_f8f6f4(
            af[i], bf[j], acc[i][j], 0, 0, 0, 0x7F7F7F7F, 0, 0x7F7F7F7F);
    if (kt + 1 < nk) {
      if (kt + 2 < nk)
        asm volatile("s_waitcnt vmcnt(4)" ::: "memory");
      else
        asm volatile("s_waitcnt vmcnt(0)" ::: "memory");
      __builtin_amdgcn_s_barrier();
    }
    cur = (cur == 2) ? 0 : cur + 1;
  }
}

// ---------------- MX-fp8 GEMM core 64(M)x128(N), 3-deep, counted vmcnt, tiled B
__device__ __forceinline__ void gemm_fp8_core64(const u8* __restrict__ A,
                                                const u8* __restrict__ B, int K,
                                                u8* Alds, u8* Blds,
                                                f32x16 (&acc)[2], int tid) {
  const int lane = tid & 63, wave = tid >> 6;
  const int h = lane >> 5, r32 = lane & 31;
  const int wrow = (wave >> 1) * 32, wcol = (wave & 1) * 64;
  const int nk = K >> 6;
  const int ra = tid >> 2, posa = tid & 3;
  const int ca = posa ^ ((ra >> 1) & 3);
  auto STAGE = [&](int t, int bb) {
    load_lds16(A + (size_t)ra * K + (size_t)t * 64 + ca * 16,
               Alds + bb * 4096 + tid * 16);
#pragma unroll
    for (int p = 0; p < 2; ++p) {
      const int s = tid + 256 * p;
      const int r = s >> 2, pos = s & 3;
      const int c = pos ^ ((r >> 1) & 3);
      load_lds16(B + (size_t)t * 8192 + r * 64 + c * 16, Blds + bb * 8192 + s * 16);
    }
  };
  STAGE(0, 0);
  STAGE(1, 1);
  asm volatile("s_waitcnt vmcnt(3)" ::: "memory");
  __builtin_amdgcn_s_barrier();
  int cur = 0;
  for (int kt = 0; kt < nk; ++kt) {
    const u8* Ac = Alds + cur * 4096;
    const u8* Bc = Blds + cur * 8192;
    i32x8 af, bf[2];
    {
      const int row = wrow + r32;
      const int sw = (row >> 1) & 3;
      i32x4 lo = *(const i32x4*)(Ac + row * 64 + ((2 * h) ^ sw) * 16);
      i32x4 hi = *(const i32x4*)(Ac + row * 64 + ((2 * h + 1) ^ sw) * 16);
      af[0] = lo[0]; af[1] = lo[1]; af[2] = lo[2]; af[3] = lo[3];
      af[4] = hi[0]; af[5] = hi[1]; af[6] = hi[2]; af[7] = hi[3];
    }
#pragma unroll
    for (int t = 0; t < 2; ++t) {
      const int row = wcol + t * 32 + r32;
      const int sw = (row >> 1) & 3;
      i32x4 lo = *(const i32x4*)(Bc + row * 64 + ((2 * h) ^ sw) * 16);
      i32x4 hi = *(const i32x4*)(Bc + row * 64 + ((2 * h + 1) ^ sw) * 16);
      i32x8 b8;
      b8[0] = lo[0]; b8[1] = lo[1]; b8[2] = lo[2]; b8[3] = lo[3];
      b8[4] = hi[0]; b8[5] = hi[1]; b8[6] = hi[2]; b8[7] = hi[3];
      bf[t] = b8;
    }
    if (kt + 2 < nk) STAGE(kt + 2, cur == 0 ? 2 : cur - 1);
#pragma unroll
    for (int j = 0; j < 2; ++j)
      acc[j] = __builtin_amdgcn_mfma_scale_f32_32x32x64_f8f6f4(
          af, bf[j], acc[j], 0, 0, 0, 0x7F7F7F7F, 0, 0x7F7F7F7F);
    if (kt + 1 < nk) {
      if (kt + 2 < nk)
        asm volatile("s_waitcnt vmcnt(3)" ::: "memory");
      else
        asm volatile("s_waitcnt vmcnt(0)" ::: "memory");
      __builtin_amdgcn_s_barrier();
    }
    cur = (cur == 2) ? 0 : cur + 1;
  }
}

// ---------------- GEMM1 + fused epilogue, XCD-chunked 1D grid (960 blocks).
// bn<16 : q/k per-head LayerNorm -> qbuf/kbuf bf16
// bn<24 : V region written DIRECTLY TRANSPOSED to vtb[bh][d][n] (k_mid gone)
// bn>=24: mlp hidden -> gelu -> gel8 fp8
__global__ __launch_bounds__(256) void k_gemm1(
    const u8* __restrict__ nx8, const u8* __restrict__ W1t,
    const float* __restrict__ b1, const float* __restrict__ qg,
    const float* __restrict__ qb_, const float* __restrict__ kg,
    const float* __restrict__ kb_, u16* __restrict__ qbuf, u16* __restrict__ kbuf,
    u16* __restrict__ vtb, u8* __restrict__ gel8) {
  __shared__ __align__(16) u8 Alds[3 * 128 * 64];
  __shared__ __align__(16) u8 Blds[3 * 128 * 64];
  const int tid = threadIdx.x;
  const int L = blockIdx.x;
  const int c = L & 7, inner = L >> 3;           // inner 0..119
  const int bm = (c & 3) * 8 + (inner & 7);
  const int bn = (c >> 2) * 15 + (inner >> 3);   // inner>>3 in 0..14
  f32x16 acc[2][2];
#pragma unroll
  for (int i = 0; i < 2; ++i)
#pragma unroll
    for (int j = 0; j < 2; ++j)
#pragma unroll
      for (int r = 0; r < 16; ++r) acc[i][j][r] = 0.f;
  gemm_fp8_core(nx8 + (size_t)bm * 128 * 1024, W1t + (size_t)bn * 128 * 1024, 1024,
                Alds, Blds, acc, tid);
  const int lane = tid & 63, wave = tid >> 6;
  const int h = lane >> 5, r32 = lane & 31;
  const int wrow = (wave >> 1) * 64, wcol = (wave & 1) * 64;
  if (bn < 16) {
    const int wc = bn * 128 + wcol;     // multiple of 64, < 2048
    const int which = wc >> 10;         // 0 = q, 1 = k
    const int head = (wc >> 6) & 15;
    const float* g = which ? kg : qg;
    const float* bb = which ? kb_ : qb_;
    const float g0 = g[r32], g1 = g[32 + r32];
    const float be0 = bb[r32], be1 = bb[32 + r32];
    const float bias0 = b1[wc + r32], bias1 = b1[wc + 32 + r32];
    u16* dst = which ? kbuf : qbuf;
#pragma unroll
    for (int i = 0; i < 2; ++i)
#pragma unroll
      for (int r = 0; r < 16; ++r) {
        float v0 = acc[i][0][r] + bias0;
        float v1 = acc[i][1][r] + bias1;
        float s = v0 + v1, ss = v0 * v0 + v1 * v1;
#pragma unroll
        for (int off = 1; off < 32; off <<= 1) {
          s += __shfl_xor(s, off);
          ss += __shfl_xor(ss, off);
        }
        const float mean = s * (1.f / 64.f);
        const float var = ss * (1.f / 64.f) - mean * mean;
        const float rstd = rsqrtf(var + 1e-5f);
        const int row = bm * 128 + wrow + i * 32 + 4 * h + (r & 3) + 8 * (r >> 2);
        const int b = row >> 10, n = row & 1023;
        u16* orow = dst + ((size_t)(b * 16 + head) * 1024 + n) * 64;
        orow[r32] = f2bf((v0 - mean) * rstd * g0 + be0);
        orow[32 + r32] = f2bf((v1 - mean) * rstd * g1 + be1);
      }
  } else if (bn < 24) {
    // V -> vtb[z = b*16+head][d][n] directly (transposed write; ushort4/8B)
#pragma unroll
    for (int i = 0; i < 2; ++i)
#pragma unroll
      for (int j = 0; j < 2; ++j) {
        const int col = bn * 128 + wcol + j * 32 + r32;
        const int cv = col - 2048;
        const int head = cv >> 6, d = cv & 63;
        const float bs = b1[col];
#pragma unroll
        for (int g2 = 0; g2 < 4; ++g2) {
          const int row0 = bm * 128 + wrow + i * 32 + 4 * h + 8 * g2;
          const int b = row0 >> 10, n = row0 & 1023;
          ushort4 st;
          st.x = f2bf(acc[i][j][4 * g2 + 0] + bs);
          st.y = f2bf(acc[i][j][4 * g2 + 1] + bs);
          st.z = f2bf(acc[i][j][4 * g2 + 2] + bs);
          st.w = f2bf(acc[i][j][4 * g2 + 3] + bs);
          *(ushort4*)(vtb + (size_t)(b * 16 + head) * 65536 + (size_t)d * 1024 +
                      n) = st;
        }
      }
  } else {
#pragma unroll
    for (int i = 0; i < 2; ++i)
#pragma unroll
      for (int j = 0; j < 2; ++j) {
        const int col = bn * 128 + wcol + j * 32 + r32;
        const int cc = col - 3072;
        const bool ok = (col < 3788);
        const float bs = ok ? b1[col] : 0.f;
#pragma unroll
        for (int r = 0; r < 16; ++r) {
          const int row = bm * 128 + wrow + i * 32 + 4 * h + (r & 3) + 8 * (r >> 2);
          float y = acc[i][j][r] + bs;
          float ge = ok ? 0.5f * y * (1.f + erff(y * 0.70710678118654752f)) : 0.f;
          gel8[(size_t)row * 768 + cc] = f2fp8(ge);
        }
      }
  }
}

// ---------------- proj + mlp fused (64-row tiles): comb[4096][2048] fp8
__global__ __launch_bounds__(256) void k_gemm_pm(
    const u8* __restrict__ xo, const u8* __restrict__ pWt,
    const u8* __restrict__ gel, const u8* __restrict__ mWt,
    u8* __restrict__ comb, const float* __restrict__ projb) {
  __shared__ __align__(16) u8 Alds[3 * 64 * 64];
  __shared__ __align__(16) u8 Blds[3 * 128 * 64];
  const int tid = threadIdx.x, bm = blockIdx.y, bnq = blockIdx.x;
  const u8* A;
  const u8* B;
  int K, colbase;
  const float* bias;
  if (bnq < 8) {
    A = xo + (size_t)bm * 64 * 1024;
    B = pWt + (size_t)bnq * 128 * 1024;
    K = 1024; colbase = bnq * 128; bias = projb;
  } else {
    A = gel + (size_t)bm * 64 * 768;
    B = mWt + (size_t)(bnq - 8) * 128 * 768;
    K = 768; colbase = 1024 + (bnq - 8) * 128; bias = nullptr;
  }
  f32x16 acc[2];
#pragma unroll
  for (int j = 0; j < 2; ++j)
#pragma unroll
    for (int r = 0; r < 16; ++r) acc[j][r] = 0.f;
  gemm_fp8_core64(A, B, K, Alds, Blds, acc, tid);
  const int lane = tid & 63, wave = tid >> 6;
  const int h = lane >> 5, r32 = lane & 31;
  const int wrow = (wave >> 1) * 32, wcol = (wave & 1) * 64;
#pragma unroll
  for (int j = 0; j < 2; ++j) {
    const int col = colbase + wcol + j * 32 + r32;
    const float bs = (bias != nullptr) ? bias[col] : 0.f;
#pragma unroll
    for (int r = 0; r < 16; ++r) {
      const int row = bm * 64 + wrow + 4 * h + (r & 3) + 8 * (r >> 2);
      comb[(size_t)row * 2048 + col] = f2fp8(acc[j][r] + bs);
    }
  }
}

// ---------------- final (64-row tiles): out = x + (comb @ W2t^T + b2) * ls_g
__global__ __launch_bounds__(256) void k_gemm_fin(const u8* __restrict__ comb,
                                                  const u8* __restrict__ W2t,
                                                  float* __restrict__ out,
                                                  const float* __restrict__ b2,
                                                  const float* __restrict__ x,
                                                  const float* __restrict__ lsg) {
  __shared__ __align__(16) u8 Alds[3 * 64 * 64];
  __shared__ __align__(16) u8 Blds[3 * 128 * 64];
  const int tid = threadIdx.x, bm = blockIdx.y, bn = blockIdx.x;
  f32x16 acc[2];
#pragma unroll
  for (int j = 0; j < 2; ++j)
#pragma unroll
    for (int r = 0; r < 16; ++r) acc[j][r] = 0.f;
  gemm_fp8_core64(comb + (size_t)bm * 64 * 2048, W2t + (size_t)bn * 128 * 2048, 2048,
                  Alds, Blds, acc, tid);
  const int lane = tid & 63, wave = tid >> 6;
  const int h = lane >> 5, r32 = lane & 31;
  const int wrow = (wave >> 1) * 32, wcol = (wave & 1) * 64;
#pragma unroll
  for (int j = 0; j < 2; ++j) {
    const int col = bn * 128 + wcol + j * 32 + r32;
    const float bs = b2[col], ls = lsg[col];
#pragma unroll
    for (int r = 0; r < 16; ++r) {
      const int row = bm * 64 + wrow + 4 * h + (r & 3) + 8 * (r >> 2);
      out[(size_t)row * 1024 + col] =
          x[(size_t)row * 1024 + col] + (acc[j][r] + bs) * ls;
    }
  }
}

// ---------------- flash attention v6: zero-barrier 1-wave blocks + T15 two-tile
// pipeline (QK(t+1) before softmax/PV(t)); counted vmcnt (T4); in-register P
// (cvt_pk + permlane32_swap, T12). 16KB LDS, grid 2048 x 64thr.
__global__ __launch_bounds__(64) void k_flash(const u16* __restrict__ q,
                                              const u16* __restrict__ k,
                                              const u16* __restrict__ vt,
                                              u8* __restrict__ xo) {
  __shared__ __align__(16) u16 Kl[2][32 * 64];
  __shared__ __align__(16) u16 Vl[2][64 * 32];
  const int lane = threadIdx.x & 63;
  const int l31 = lane & 31, h = lane >> 5;
  const int L = blockIdx.x;
  const int xcd = L & 7, i = L >> 3;
  const int bh = xcd * 8 + (i & 7);
  const int qt = i >> 3;
  const int qrow0 = qt * 32;
  const u16* qb = q + ((size_t)bh * 1024 + qrow0) * 64;
  const u16* kb = k + (size_t)bh * 1024 * 64;
  const u16* vb = vt + (size_t)bh * 64 * 1024;

  u16x8 qf[4];
#pragma unroll
  for (int ds = 0; ds < 4; ++ds)
    qf[ds] = *(const u16x8*)(qb + (size_t)l31 * 64 + ds * 16 + h * 8);
  asm volatile("s_waitcnt vmcnt(0)" ::: "memory");

  f32x16 O[2];
#pragma unroll
  for (int d2 = 0; d2 < 2; ++d2)
#pragma unroll
    for (int r = 0; r < 16; ++r) O[d2][r] = 0.f;
  float lacc = 0.f;

  auto STAGE = [&](int t, int bb) {
#pragma unroll
    for (int p = 0; p < 4; ++p) {
      const int s = lane + 64 * p;
      const int kr = s >> 3, kslot = s & 7;
      const int kc = kslot ^ ((kr ^ (kr >> 3)) & 7);
      load_lds16(kb + (size_t)(t * 32 + kr) * 64 + kc * 8, (u16*)Kl[bb] + s * 8);
      const int vr = s >> 2, vslot = s & 3;
      const int vc = vslot ^ ((vr >> 1) & 3);
      load_lds16(vb + (size_t)vr * 1024 + t * 32 + vc * 8, (u16*)Vl[bb] + s * 8);
    }
  };
  STAGE(0, 0);
  STAGE(1, 1);

  const int swzk = (l31 & 7) ^ ((l31 >> 3) & 3);
  const float C = 0.18033688011112042f;  // 0.125 * log2(e)

  f32x16 Sa, Sb;
  u16x8 vfA[4], vfB[4];

  auto READ_FRAGS = [&](int t, u16x8 (&kf)[4], u16x8 (&vf)[4]) {
    const u16* Kc = (const u16*)Kl[t & 1];
    const u16* Vc = (const u16*)Vl[t & 1];
#pragma unroll
    for (int ds = 0; ds < 4; ++ds)
      kf[ds] = *(const u16x8*)(Kc + l31 * 64 + (((ds * 2 + h) ^ swzk)) * 8);
#pragma unroll
    for (int m = 0; m < 2; ++m)
#pragma unroll
      for (int d2 = 0; d2 < 2; ++d2) {
        const int vr = d2 * 32 + l31;
        const int pos = (m * 2 + h) ^ ((vr >> 1) & 3);
        vf[m * 2 + d2] = *(const u16x8*)(Vc + vr * 32 + pos * 8);
      }
  };

  // prologue: tile 0 -> Sa, vfA
  {
    asm volatile("s_waitcnt vmcnt(8)" ::: "memory");
    u16x8 kf[4];
    READ_FRAGS(0, kf, vfA);
    asm volatile("s_waitcnt lgkmcnt(0)" ::: "memory");
    __builtin_amdgcn_sched_barrier(0);
    STAGE(2, 0);
#pragma unroll
    for (int r = 0; r < 16; ++r) Sa[r] = 0.f;
    __builtin_amdgcn_s_setprio(1);
#pragma unroll
    for (int ds = 0; ds < 4; ++ds) Sa = mfma32(kf[ds], qf[ds], Sa);
    __builtin_amdgcn_s_setprio(0);
  }

  auto TILE = [&](int t, f32x16& Sc, f32x16& Sn, u16x8 (&vc)[4], u16x8 (&vn)[4]) {
    if (t < 31) {
      if (t <= 29)
        asm volatile("s_waitcnt vmcnt(8)" ::: "memory");
      else
        asm volatile("s_waitcnt vmcnt(0)" ::: "memory");
      u16x8 kf[4];
      READ_FRAGS(t + 1, kf, vn);
      asm volatile("s_waitcnt lgkmcnt(0)" ::: "memory");
      __builtin_amdgcn_sched_barrier(0);
      if (t + 3 < 32) STAGE(t + 3, (t + 3) & 1);
#pragma unroll
      for (int r = 0; r < 16; ++r) Sn[r] = 0.f;
      __builtin_amdgcn_s_setprio(1);
#pragma unroll
      for (int ds = 0; ds < 4; ++ds) Sn = mfma32(kf[ds], qf[ds], Sn);
      __builtin_amdgcn_s_setprio(0);
    }
#pragma unroll
    for (int r = 0; r < 16; ++r) {
      float pv = exp2_fast(Sc[r] * C);
      Sc[r] = pv;
      lacc += pv;
    }
    __builtin_amdgcn_s_setprio(1);
#pragma unroll
    for (int m = 0; m < 2; ++m) {
      const int ro = m * 8;
      unsigned w0 = cvtpk_bf16(Sc[ro + 0], Sc[ro + 1]);
      unsigned w2 = cvtpk_bf16(Sc[ro + 4], Sc[ro + 5]);
      unsigned w1 = cvtpk_bf16(Sc[ro + 2], Sc[ro + 3]);
      unsigned w3 = cvtpk_bf16(Sc[ro + 6], Sc[ro + 7]);
      plswap(w0, w2);
      plswap(w1, w3);
      i32x4 aw;
      aw[0] = (int)w0; aw[1] = (int)w1; aw[2] = (int)w2; aw[3] = (int)w3;
      const u16x8 pa = __builtin_bit_cast(u16x8, aw);
#pragma unroll
      for (int d2 = 0; d2 < 2; ++d2) O[d2] = mfma32(pa, vc[m * 2 + d2], O[d2]);
    }
    __builtin_amdgcn_s_setprio(0);
  };

  for (int t = 0; t < 32; t += 2) {
    TILE(t, Sa, Sb, vfA, vfB);
    TILE(t + 1, Sb, Sa, vfB, vfA);
  }

  lacc += __shfl_xor(lacc, 32);
  const float inv = 1.f / lacc;
  const int b = bh >> 4, hh = bh & 15;
#pragma unroll
  for (int r = 0; r < 16; ++r) {
    const int qr = (r & 3) + 8 * (r >> 2) + 4 * h;
    const float invr = __shfl(inv, qr);
    u8* orow = xo + (size_t)(b * 1024 + qrow0 + qr) * 1024 + hh * 64;
    orow[l31] = f2fp8(O[0][r] * invr);
    orow[32 + l31] = f2fp8(O[1][r] * invr);
  }
}

extern "C" void kernel_launch(void* const* d_in, const int* in_sizes, int n_in,
                              void* d_out, int out_size, void* d_ws, size_t ws_size,
                              hipStream_t stream) {
  (void)in_sizes; (void)n_in; (void)out_size; (void)ws_size;
  const float* x      = (const float*)d_in[0];
  const float* norm_g = (const float*)d_in[1];
  const float* norm_b = (const float*)d_in[2];
  const float* W1     = (const float*)d_in[3];
  const float* b1     = (const float*)d_in[4];
  const float* qn_g   = (const float*)d_in[5];
  const float* qn_b   = (const float*)d_in[6];
  const float* kn_g   = (const float*)d_in[7];
  const float* kn_b   = (const float*)d_in[8];
  const float* projW  = (const float*)d_in[9];
  const float* projb  = (const float*)d_in[10];
  const float* mlpW   = (const float*)d_in[11];
  const float* W2     = (const float*)d_in[12];
  const float* b2     = (const float*)d_in[13];
  const float* ls_g   = (const float*)d_in[14];

  char* ws = (char*)d_ws;
  u8*  W1t8 = (u8*)(ws + 0);           // [3840][1024]  3,932,160 (K-tiled)
  u8*  pWt8 = (u8*)(ws + 3932160);     // [1024][1024]  1,048,576 (K-tiled)
  u8*  mWt8 = (u8*)(ws + 4980736);     // [1024][768]     786,432 (K-tiled)
  u8*  W2t8 = (u8*)(ws + 5767168);     // [1024][2048]  2,097,152 (K-tiled)
  u8*  nx8  = (u8*)(ws + 7864320);     // [4096][1024]  4,194,304 (then xo8)
  u16* f1   = (u16*)(ws + 12058624);   // (comb fp8 region)
  u16* qbuf = (u16*)(ws + 43515904);   // [64][1024][64] 8,388,608
  u16* kbuf = (u16*)(ws + 51904512);   // [64][1024][64] 8,388,608
  u16* vtb  = (u16*)(ws + 60293120);   // [64][64][1024] 8,388,608
  u8*  gel8 = (u8*)(ws + 68681728);    // [4096][768]   3,145,728

  k_pre<<<6016, 256, 0, stream>>>(W1, projW, mlpW, W2, W1t8, pWt8, mWt8, W2t8,
                                  x, norm_g, norm_b, nx8);
  k_gemm1<<<960, 256, 0, stream>>>(nx8, W1t8, b1, qn_g, qn_b, kn_g, kn_b,
                                   qbuf, kbuf, vtb, gel8);
  k_flash<<<2048, 64, 0, stream>>>(qbuf, kbuf, vtb, nx8);
  k_gemm_pm<<<dim3(16, 64), 256, 0, stream>>>(nx8, pWt8, gel8, mWt8, (u8*)f1, projb);
  k_gemm_fin<<<dim3(8, 64), 256, 0, stream>>>((u8*)f1, W2t8, (float*)d_out, b2, x,
                                              ls_g);
}

// Round 11
// 219.216 us; speedup vs baseline: 1.0674x; 1.0218x over previous
//
#include <hip/hip_runtime.h>
#include <cstdint>
#include <cstddef>

typedef unsigned short u16;
typedef unsigned char u8;
typedef __attribute__((ext_vector_type(8))) u16 u16x8;
typedef __attribute__((ext_vector_type(8))) __bf16 bf16x8;
typedef __attribute__((ext_vector_type(4))) float f32x4;
typedef __attribute__((ext_vector_type(16))) float f32x16;
typedef __attribute__((ext_vector_type(4))) int i32x4;
typedef __attribute__((ext_vector_type(8))) int i32x8;
typedef __attribute__((ext_vector_type(2))) int i32x2;

__device__ __forceinline__ u16 f2bf(float f) {
  unsigned u = __builtin_bit_cast(unsigned, f);
  return (u16)((u + 0x7FFFu + ((u >> 16) & 1u)) >> 16);
}
__device__ __forceinline__ float bf2f(u16 h) {
  return __builtin_bit_cast(float, (unsigned)h << 16);
}
__device__ __forceinline__ u8 f2fp8(float f) {
  return (u8)(__builtin_amdgcn_cvt_pk_fp8_f32(f, 0.f, 0, false) & 0xFF);
}
__device__ __forceinline__ f32x16 mfma32(u16x8 a, u16x8 b, f32x16 c) {
  return __builtin_amdgcn_mfma_f32_32x32x16_bf16(
      __builtin_bit_cast(bf16x8, a), __builtin_bit_cast(bf16x8, b), c, 0, 0, 0);
}
__device__ __forceinline__ unsigned cvtpk_bf16(float lo, float hi) {
  unsigned r;
  asm("v_cvt_pk_bf16_f32 %0, %1, %2" : "=v"(r) : "v"(lo), "v"(hi));
  return r;
}
__device__ __forceinline__ float exp2_fast(float x) {
  float r;
  asm("v_exp_f32 %0, %1" : "=v"(r) : "v"(x));
  return r;
}
__device__ __forceinline__ void plswap(unsigned& a, unsigned& b) {
  i32x2 r = __builtin_amdgcn_permlane32_swap((int)a, (int)b, false, false);
  a = (unsigned)r[0];
  b = (unsigned)r[1];
}
__device__ __forceinline__ void load_lds16(const void* g, void* l) {
  __builtin_amdgcn_global_load_lds(
      (const __attribute__((address_space(1))) void*)g,
      (__attribute__((address_space(3))) void*)l, 16, 0, 0);
}

// ---------------- fused pre-pass v2: 64x64 transpose tiles (fp8 K-tiled, fully
// coalesced: 256B-row reads, one 16B i32x4 store/thread into a 4KB stream) +
// x LayerNorm. L < 1920: tiles (W1 960, proj 256, mlp 192, W2 512); else LN rows.
__global__ __launch_bounds__(256) void k_pre(
    const float* __restrict__ W1, const float* __restrict__ projW,
    const float* __restrict__ mlpW, const float* __restrict__ W2,
    u8* __restrict__ W1t, u8* __restrict__ pWt, u8* __restrict__ mWt,
    u8* __restrict__ W2t, const float* __restrict__ x,
    const float* __restrict__ g, const float* __restrict__ b,
    u8* __restrict__ nx8) {
  __shared__ float tt[64][65];
  __shared__ float red[8];
  const int L = blockIdx.x;
  const int tid = threadIdx.x;
  if (L < 1920) {
    const float* src;
    u8* dst;
    int R, C, nkt, bx, by;
    if (L < 960) {
      src = W1; dst = W1t; R = 1024; C = 3788; nkt = 16; bx = L / 16; by = L % 16;
    } else if (L < 1216) {
      int t = L - 960;
      src = projW; dst = pWt; R = 1024; C = 1024; nkt = 16; bx = t / 16; by = t % 16;
    } else if (L < 1408) {
      int t = L - 1216;
      src = mlpW; dst = mWt; R = 716; C = 1024; nkt = 12; bx = t / 12; by = t % 12;
    } else {
      int t = L - 1408;
      src = W2; dst = W2t; R = 2048; C = 1024; nkt = 32; bx = t / 32; by = t % 32;
    }
    const int n0 = bx * 64, k0 = by * 64;
    const int lr = tid >> 6, lc = tid & 63;
#pragma unroll
    for (int j = 0; j < 16; ++j) {
      const int kk = k0 + lr + 4 * j, nn = n0 + lc;
      tt[lr + 4 * j][lc] = (kk < R && nn < C) ? src[(size_t)kk * C + nn] : 0.f;
    }
    __syncthreads();
    const int rn = tid >> 2;        // local n row 0..63
    const int kb = (tid & 3) * 16;  // k-byte offset 0,16,32,48
    i32x4 st;
#pragma unroll
    for (int w = 0; w < 4; ++w) {
      int p0 = __builtin_amdgcn_cvt_pk_fp8_f32(tt[kb + 4 * w + 0][rn],
                                               tt[kb + 4 * w + 1][rn], 0, false);
      p0 = __builtin_amdgcn_cvt_pk_fp8_f32(tt[kb + 4 * w + 2][rn],
                                           tt[kb + 4 * w + 3][rn], p0, true);
      st[w] = p0;
    }
    const int nn_g = n0 + rn;
    const int p = nn_g >> 7, rr = nn_g & 127;
    *(i32x4*)(dst + ((size_t)(p * nkt + by) * 128 + rr) * 64 + kb) = st;
  } else {
    const int row = L - 1920;
    float4 v = ((const float4*)(x + (size_t)row * 1024))[tid];
    float s = v.x + v.y + v.z + v.w;
    float ss = v.x * v.x + v.y * v.y + v.z * v.z + v.w * v.w;
#pragma unroll
    for (int off = 1; off < 64; off <<= 1) {
      s += __shfl_xor(s, off);
      ss += __shfl_xor(ss, off);
    }
    const int wid = tid >> 6, lane = tid & 63;
    if (lane == 0) { red[wid] = s; red[4 + wid] = ss; }
    __syncthreads();
    s = red[0] + red[1] + red[2] + red[3];
    ss = red[4] + red[5] + red[6] + red[7];
    const float mean = s * (1.f / 1024.f);
    const float var = ss * (1.f / 1024.f) - mean * mean;
    const float rstd = rsqrtf(var + 1e-5f);
    float4 gv = ((const float4*)g)[tid];
    float4 bv = ((const float4*)b)[tid];
    float y0 = (v.x - mean) * rstd * gv.x + bv.x;
    float y1 = (v.y - mean) * rstd * gv.y + bv.y;
    float y2 = (v.z - mean) * rstd * gv.z + bv.z;
    float y3 = (v.w - mean) * rstd * gv.w + bv.w;
    int pk = __builtin_amdgcn_cvt_pk_fp8_f32(y0, y1, 0, false);
    pk = __builtin_amdgcn_cvt_pk_fp8_f32(y2, y3, pk, true);
    ((int*)(nx8 + (size_t)row * 1024))[tid] = pk;
  }
}

// ---------------- MX-fp8 GEMM core 128x128, 3-deep pipeline, counted vmcnt,
// ONE barrier per K-step. B is K-TILED: B + kt*8192 + row*64 (contiguous 8KB).
__device__ __forceinline__ void gemm_fp8_core(const u8* __restrict__ A,
                                              const u8* __restrict__ B, int K,
                                              u8* Alds, u8* Blds,
                                              f32x16 (&acc)[2][2], int tid) {
  const int lane = tid & 63, wave = tid >> 6;
  const int h = lane >> 5, r32 = lane & 31;
  const int wrow = (wave >> 1) * 64, wcol = (wave & 1) * 64;
  const int srow0 = tid >> 2, spos = tid & 3;
  const int nk = K >> 6;
  auto STAGE = [&](int t, int bb) {
#pragma unroll
    for (int p = 0; p < 2; ++p) {
      const int row = p * 64 + srow0;
      const int c = spos ^ ((row >> 1) & 3);
      load_lds16(A + (size_t)row * K + (size_t)t * 64 + c * 16,
                 Alds + bb * 8192 + (p * 256 + tid) * 16);
      load_lds16(B + (size_t)t * 8192 + row * 64 + c * 16,
                 Blds + bb * 8192 + (p * 256 + tid) * 16);
    }
  };
  STAGE(0, 0);
  STAGE(1, 1);
  asm volatile("s_waitcnt vmcnt(4)" ::: "memory");
  __builtin_amdgcn_s_barrier();
  int cur = 0;
  for (int kt = 0; kt < nk; ++kt) {
    const u8* Ac = Alds + cur * 8192;
    const u8* Bc = Blds + cur * 8192;
    i32x8 af[2], bf[2];
#pragma unroll
    for (int t = 0; t < 2; ++t) {
      {
        const int row = wrow + t * 32 + r32;
        const int sw = (row >> 1) & 3;
        i32x4 lo = *(const i32x4*)(Ac + row * 64 + ((2 * h) ^ sw) * 16);
        i32x4 hi = *(const i32x4*)(Ac + row * 64 + ((2 * h + 1) ^ sw) * 16);
        i32x8 a;
        a[0] = lo[0]; a[1] = lo[1]; a[2] = lo[2]; a[3] = lo[3];
        a[4] = hi[0]; a[5] = hi[1]; a[6] = hi[2]; a[7] = hi[3];
        af[t] = a;
      }
      {
        const int row = wcol + t * 32 + r32;
        const int sw = (row >> 1) & 3;
        i32x4 lo = *(const i32x4*)(Bc + row * 64 + ((2 * h) ^ sw) * 16);
        i32x4 hi = *(const i32x4*)(Bc + row * 64 + ((2 * h + 1) ^ sw) * 16);
        i32x8 b8;
        b8[0] = lo[0]; b8[1] = lo[1]; b8[2] = lo[2]; b8[3] = lo[3];
        b8[4] = hi[0]; b8[5] = hi[1]; b8[6] = hi[2]; b8[7] = hi[3];
        bf[t] = b8;
      }
    }
    if (kt + 2 < nk) STAGE(kt + 2, cur == 0 ? 2 : cur - 1);
#pragma unroll
    for (int i = 0; i < 2; ++i)
#pragma unroll
      for (int j = 0; j < 2; ++j)
        acc[i][j] = __builtin_amdgcn_mfma_scale_f32_32x32x64_f8f6f4(
            af[i], bf[j], acc[i][j], 0, 0, 0, 0x7F7F7F7F, 0, 0x7F7F7F7F);
    if (kt + 1 < nk) {
      if (kt + 2 < nk)
        asm volatile("s_waitcnt vmcnt(4)" ::: "memory");
      else
        asm volatile("s_waitcnt vmcnt(0)" ::: "memory");
      __builtin_amdgcn_s_barrier();
    }
    cur = (cur == 2) ? 0 : cur + 1;
  }
}

// ---------------- MX-fp8 GEMM core 64(M)x128(N), 3-deep, counted vmcnt, tiled B
__device__ __forceinline__ void gemm_fp8_core64(const u8* __restrict__ A,
                                                const u8* __restrict__ B, int K,
                                                u8* Alds, u8* Blds,
                                                f32x16 (&acc)[2], int tid) {
  const int lane = tid & 63, wave = tid >> 6;
  const int h = lane >> 5, r32 = lane & 31;
  const int wrow = (wave >> 1) * 32, wcol = (wave & 1) * 64;
  const int nk = K >> 6;
  const int ra = tid >> 2, posa = tid & 3;
  const int ca = posa ^ ((ra >> 1) & 3);
  auto STAGE = [&](int t, int bb) {
    load_lds16(A + (size_t)ra * K + (size_t)t * 64 + ca * 16,
               Alds + bb * 4096 + tid * 16);
#pragma unroll
    for (int p = 0; p < 2; ++p) {
      const int s = tid + 256 * p;
      const int r = s >> 2, pos = s & 3;
      const int c = pos ^ ((r >> 1) & 3);
      load_lds16(B + (size_t)t * 8192 + r * 64 + c * 16, Blds + bb * 8192 + s * 16);
    }
  };
  STAGE(0, 0);
  STAGE(1, 1);
  asm volatile("s_waitcnt vmcnt(3)" ::: "memory");
  __builtin_amdgcn_s_barrier();
  int cur = 0;
  for (int kt = 0; kt < nk; ++kt) {
    const u8* Ac = Alds + cur * 4096;
    const u8* Bc = Blds + cur * 8192;
    i32x8 af, bf[2];
    {
      const int row = wrow + r32;
      const int sw = (row >> 1) & 3;
      i32x4 lo = *(const i32x4*)(Ac + row * 64 + ((2 * h) ^ sw) * 16);
      i32x4 hi = *(const i32x4*)(Ac + row * 64 + ((2 * h + 1) ^ sw) * 16);
      af[0] = lo[0]; af[1] = lo[1]; af[2] = lo[2]; af[3] = lo[3];
      af[4] = hi[0]; af[5] = hi[1]; af[6] = hi[2]; af[7] = hi[3];
    }
#pragma unroll
    for (int t = 0; t < 2; ++t) {
      const int row = wcol + t * 32 + r32;
      const int sw = (row >> 1) & 3;
      i32x4 lo = *(const i32x4*)(Bc + row * 64 + ((2 * h) ^ sw) * 16);
      i32x4 hi = *(const i32x4*)(Bc + row * 64 + ((2 * h + 1) ^ sw) * 16);
      i32x8 b8;
      b8[0] = lo[0]; b8[1] = lo[1]; b8[2] = lo[2]; b8[3] = lo[3];
      b8[4] = hi[0]; b8[5] = hi[1]; b8[6] = hi[2]; b8[7] = hi[3];
      bf[t] = b8;
    }
    if (kt + 2 < nk) STAGE(kt + 2, cur == 0 ? 2 : cur - 1);
#pragma unroll
    for (int j = 0; j < 2; ++j)
      acc[j] = __builtin_amdgcn_mfma_scale_f32_32x32x64_f8f6f4(
          af, bf[j], acc[j], 0, 0, 0, 0x7F7F7F7F, 0, 0x7F7F7F7F);
    if (kt + 1 < nk) {
      if (kt + 2 < nk)
        asm volatile("s_waitcnt vmcnt(3)" ::: "memory");
      else
        asm volatile("s_waitcnt vmcnt(0)" ::: "memory");
      __builtin_amdgcn_s_barrier();
    }
    cur = (cur == 2) ? 0 : cur + 1;
  }
}

// ---------------- GEMM1 + fused epilogue, XCD-chunked 1D grid (960 blocks).
// bn<16 : q/k per-head LayerNorm -> qbuf/kbuf bf16
// bn<24 : V -> vtb[bh][d][n], COALESCED via LDS block-transpose (16B stores of
//         8 consecutive n). FIX vs round 10: n is the WITHIN-BATCH row
//         ((bm&7)*128 + ...), not the global token row (bm*128 + ...).
// bn>=24: mlp hidden -> gelu -> gel8 fp8
__global__ __launch_bounds__(256) void k_gemm1(
    const u8* __restrict__ nx8, const u8* __restrict__ W1t,
    const float* __restrict__ b1, const float* __restrict__ qg,
    const float* __restrict__ qb_, const float* __restrict__ kg,
    const float* __restrict__ kb_, u16* __restrict__ qbuf, u16* __restrict__ kbuf,
    u16* __restrict__ vtb, u8* __restrict__ gel8) {
  __shared__ __align__(16) u8 Alds[3 * 128 * 64];
  __shared__ __align__(16) u8 Blds[3 * 128 * 64];
  const int tid = threadIdx.x;
  const int L = blockIdx.x;
  const int c = L & 7, inner = L >> 3;           // inner 0..119
  const int bm = (c & 3) * 8 + (inner & 7);
  const int bn = (c >> 2) * 15 + (inner >> 3);   // inner>>3 in 0..14
  f32x16 acc[2][2];
#pragma unroll
  for (int i = 0; i < 2; ++i)
#pragma unroll
    for (int j = 0; j < 2; ++j)
#pragma unroll
      for (int r = 0; r < 16; ++r) acc[i][j][r] = 0.f;
  gemm_fp8_core(nx8 + (size_t)bm * 128 * 1024, W1t + (size_t)bn * 128 * 1024, 1024,
                Alds, Blds, acc, tid);
  const int lane = tid & 63, wave = tid >> 6;
  const int h = lane >> 5, r32 = lane & 31;
  const int wrow = (wave >> 1) * 64, wcol = (wave & 1) * 64;
  if (bn < 16) {
    const int wc = bn * 128 + wcol;     // multiple of 64, < 2048
    const int which = wc >> 10;         // 0 = q, 1 = k
    const int head = (wc >> 6) & 15;
    const float* g = which ? kg : qg;
    const float* bb = which ? kb_ : qb_;
    const float g0 = g[r32], g1 = g[32 + r32];
    const float be0 = bb[r32], be1 = bb[32 + r32];
    const float bias0 = b1[wc + r32], bias1 = b1[wc + 32 + r32];
    u16* dst = which ? kbuf : qbuf;
#pragma unroll
    for (int i = 0; i < 2; ++i)
#pragma unroll
      for (int r = 0; r < 16; ++r) {
        float v0 = acc[i][0][r] + bias0;
        float v1 = acc[i][1][r] + bias1;
        float s = v0 + v1, ss = v0 * v0 + v1 * v1;
#pragma unroll
        for (int off = 1; off < 32; off <<= 1) {
          s += __shfl_xor(s, off);
          ss += __shfl_xor(ss, off);
        }
        const float mean = s * (1.f / 64.f);
        const float var = ss * (1.f / 64.f) - mean * mean;
        const float rstd = rsqrtf(var + 1e-5f);
        const int row = bm * 128 + wrow + i * 32 + 4 * h + (r & 3) + 8 * (r >> 2);
        const int b = row >> 10, n = row & 1023;
        u16* orow = dst + ((size_t)(b * 16 + head) * 1024 + n) * 64;
        orow[r32] = f2bf((v0 - mean) * rstd * g0 + be0);
        orow[32 + r32] = f2bf((v1 - mean) * rstd * g1 + be1);
      }
  } else if (bn < 24) {
    // V tile (128 n-rows x 128 cv-cols) -> LDS transpose -> coalesced vtb write.
    // vbuf aliases the (now idle) GEMM staging LDS: [128 c][66 r] u16, 16.9KB.
    u16* vbuf = (u16*)Alds;
    const int cbase = bn * 128 - 2048;      // cv of c_local=0 (multiple of 128)
    const int bq = bm >> 3;                 // batch index (uniform per block)
    const int nb = (bm & 7) * 128;          // within-batch row base (FIX)
#pragma unroll
    for (int i = 0; i < 2; ++i) {
      __syncthreads();                      // staging LDS free / prev pass done
#pragma unroll
      for (int j = 0; j < 2; ++j) {
        const int c_local = wcol + j * 32 + r32;
        const float bs = b1[2048 + cbase + c_local];
#pragma unroll
        for (int r = 0; r < 16; ++r) {
          const int rl = (wrow >> 6) * 32 + 4 * h + (r & 3) + 8 * (r >> 2);
          vbuf[c_local * 66 + rl] = f2bf(acc[i][j][r] + bs);
        }
      }
      __syncthreads();
      // stream out: 4 reps x 256 thr; each writes 8 consecutive n (16B store)
#pragma unroll
      for (int rep = 0; rep < 4; ++rep) {
        const int idx = tid + 256 * rep;    // 0..1023
        const int cl = idx >> 3, chunk = idx & 7;
        const int head = (cbase + cl) >> 6, d = (cbase + cl) & 63;
        const int rl0 = (chunk >> 2) * 32 + (chunk & 3) * 8;
        const int n = nb + (chunk >> 2) * 64 + i * 32 + (chunk & 3) * 8;
        u16x8 st;
#pragma unroll
        for (int e = 0; e < 8; ++e) st[e] = vbuf[cl * 66 + rl0 + e];
        *(u16x8*)(vtb + (size_t)(bq * 16 + head) * 65536 + (size_t)d * 1024 + n) =
            st;
      }
    }
  } else {
#pragma unroll
    for (int i = 0; i < 2; ++i)
#pragma unroll
      for (int j = 0; j < 2; ++j) {
        const int col = bn * 128 + wcol + j * 32 + r32;
        const int cc = col - 3072;
        const bool ok = (col < 3788);
        const float bs = ok ? b1[col] : 0.f;
#pragma unroll
        for (int r = 0; r < 16; ++r) {
          const int row = bm * 128 + wrow + i * 32 + 4 * h + (r & 3) + 8 * (r >> 2);
          float y = acc[i][j][r] + bs;
          float ge = ok ? 0.5f * y * (1.f + erff(y * 0.70710678118654752f)) : 0.f;
          gel8[(size_t)row * 768 + cc] = f2fp8(ge);
        }
      }
  }
}

// ---------------- proj + mlp fused (64-row tiles): comb[4096][2048] fp8
__global__ __launch_bounds__(256) void k_gemm_pm(
    const u8* __restrict__ xo, const u8* __restrict__ pWt,
    const u8* __restrict__ gel, const u8* __restrict__ mWt,
    u8* __restrict__ comb, const float* __restrict__ projb) {
  __shared__ __align__(16) u8 Alds[3 * 64 * 64];
  __shared__ __align__(16) u8 Blds[3 * 128 * 64];
  const int tid = threadIdx.x, bm = blockIdx.y, bnq = blockIdx.x;
  const u8* A;
  const u8* B;
  int K, colbase;
  const float* bias;
  if (bnq < 8) {
    A = xo + (size_t)bm * 64 * 1024;
    B = pWt + (size_t)bnq * 128 * 1024;
    K = 1024; colbase = bnq * 128; bias = projb;
  } else {
    A = gel + (size_t)bm * 64 * 768;
    B = mWt + (size_t)(bnq - 8) * 128 * 768;
    K = 768; colbase = 1024 + (bnq - 8) * 128; bias = nullptr;
  }
  f32x16 acc[2];
#pragma unroll
  for (int j = 0; j < 2; ++j)
#pragma unroll
    for (int r = 0; r < 16; ++r) acc[j][r] = 0.f;
  gemm_fp8_core64(A, B, K, Alds, Blds, acc, tid);
  const int lane = tid & 63, wave = tid >> 6;
  const int h = lane >> 5, r32 = lane & 31;
  const int wrow = (wave >> 1) * 32, wcol = (wave & 1) * 64;
#pragma unroll
  for (int j = 0; j < 2; ++j) {
    const int col = colbase + wcol + j * 32 + r32;
    const float bs = (bias != nullptr) ? bias[col] : 0.f;
#pragma unroll
    for (int r = 0; r < 16; ++r) {
      const int row = bm * 64 + wrow + 4 * h + (r & 3) + 8 * (r >> 2);
      comb[(size_t)row * 2048 + col] = f2fp8(acc[j][r] + bs);
    }
  }
}

// ---------------- final (64-row tiles): out = x + (comb @ W2t^T + b2) * ls_g
__global__ __launch_bounds__(256) void k_gemm_fin(const u8* __restrict__ comb,
                                                  const u8* __restrict__ W2t,
                                                  float* __restrict__ out,
                                                  const float* __restrict__ b2,
                                                  const float* __restrict__ x,
                                                  const float* __restrict__ lsg) {
  __shared__ __align__(16) u8 Alds[3 * 64 * 64];
  __shared__ __align__(16) u8 Blds[3 * 128 * 64];
  const int tid = threadIdx.x, bm = blockIdx.y, bn = blockIdx.x;
  f32x16 acc[2];
#pragma unroll
  for (int j = 0; j < 2; ++j)
#pragma unroll
    for (int r = 0; r < 16; ++r) acc[j][r] = 0.f;
  gemm_fp8_core64(comb + (size_t)bm * 64 * 2048, W2t + (size_t)bn * 128 * 2048, 2048,
                  Alds, Blds, acc, tid);
  const int lane = tid & 63, wave = tid >> 6;
  const int h = lane >> 5, r32 = lane & 31;
  const int wrow = (wave >> 1) * 32, wcol = (wave & 1) * 64;
#pragma unroll
  for (int j = 0; j < 2; ++j) {
    const int col = bn * 128 + wcol + j * 32 + r32;
    const float bs = b2[col], ls = lsg[col];
#pragma unroll
    for (int r = 0; r < 16; ++r) {
      const int row = bm * 64 + wrow + 4 * h + (r & 3) + 8 * (r >> 2);
      out[(size_t)row * 1024 + col] =
          x[(size_t)row * 1024 + col] + (acc[j][r] + bs) * ls;
    }
  }
}

// ---------------- flash attention v6: zero-barrier 1-wave blocks + T15 two-tile
// pipeline (QK(t+1) before softmax/PV(t)); counted vmcnt (T4); in-register P
// (cvt_pk + permlane32_swap, T12). 16KB LDS, grid 2048 x 64thr.
__global__ __launch_bounds__(64) void k_flash(const u16* __restrict__ q,
                                              const u16* __restrict__ k,
                                              const u16* __restrict__ vt,
                                              u8* __restrict__ xo) {
  __shared__ __align__(16) u16 Kl[2][32 * 64];
  __shared__ __align__(16) u16 Vl[2][64 * 32];
  const int lane = threadIdx.x & 63;
  const int l31 = lane & 31, h = lane >> 5;
  const int L = blockIdx.x;
  const int xcd = L & 7, i = L >> 3;
  const int bh = xcd * 8 + (i & 7);
  const int qt = i >> 3;
  const int qrow0 = qt * 32;
  const u16* qb = q + ((size_t)bh * 1024 + qrow0) * 64;
  const u16* kb = k + (size_t)bh * 1024 * 64;
  const u16* vb = vt + (size_t)bh * 64 * 1024;

  u16x8 qf[4];
#pragma unroll
  for (int ds = 0; ds < 4; ++ds)
    qf[ds] = *(const u16x8*)(qb + (size_t)l31 * 64 + ds * 16 + h * 8);
  asm volatile("s_waitcnt vmcnt(0)" ::: "memory");

  f32x16 O[2];
#pragma unroll
  for (int d2 = 0; d2 < 2; ++d2)
#pragma unroll
    for (int r = 0; r < 16; ++r) O[d2][r] = 0.f;
  float lacc = 0.f;

  auto STAGE = [&](int t, int bb) {
#pragma unroll
    for (int p = 0; p < 4; ++p) {
      const int s = lane + 64 * p;
      const int kr = s >> 3, kslot = s & 7;
      const int kc = kslot ^ ((kr ^ (kr >> 3)) & 7);
      load_lds16(kb + (size_t)(t * 32 + kr) * 64 + kc * 8, (u16*)Kl[bb] + s * 8);
      const int vr = s >> 2, vslot = s & 3;
      const int vc = vslot ^ ((vr >> 1) & 3);
      load_lds16(vb + (size_t)vr * 1024 + t * 32 + vc * 8, (u16*)Vl[bb] + s * 8);
    }
  };
  STAGE(0, 0);
  STAGE(1, 1);

  const int swzk = (l31 & 7) ^ ((l31 >> 3) & 3);
  const float C = 0.18033688011112042f;  // 0.125 * log2(e)

  f32x16 Sa, Sb;
  u16x8 vfA[4], vfB[4];

  auto READ_FRAGS = [&](int t, u16x8 (&kf)[4], u16x8 (&vf)[4]) {
    const u16* Kc = (const u16*)Kl[t & 1];
    const u16* Vc = (const u16*)Vl[t & 1];
#pragma unroll
    for (int ds = 0; ds < 4; ++ds)
      kf[ds] = *(const u16x8*)(Kc + l31 * 64 + (((ds * 2 + h) ^ swzk)) * 8);
#pragma unroll
    for (int m = 0; m < 2; ++m)
#pragma unroll
      for (int d2 = 0; d2 < 2; ++d2) {
        const int vr = d2 * 32 + l31;
        const int pos = (m * 2 + h) ^ ((vr >> 1) & 3);
        vf[m * 2 + d2] = *(const u16x8*)(Vc + vr * 32 + pos * 8);
      }
  };

  // prologue: tile 0 -> Sa, vfA
  {
    asm volatile("s_waitcnt vmcnt(8)" ::: "memory");
    u16x8 kf[4];
    READ_FRAGS(0, kf, vfA);
    asm volatile("s_waitcnt lgkmcnt(0)" ::: "memory");
    __builtin_amdgcn_sched_barrier(0);
    STAGE(2, 0);
#pragma unroll
    for (int r = 0; r < 16; ++r) Sa[r] = 0.f;
    __builtin_amdgcn_s_setprio(1);
#pragma unroll
    for (int ds = 0; ds < 4; ++ds) Sa = mfma32(kf[ds], qf[ds], Sa);
    __builtin_amdgcn_s_setprio(0);
  }

  auto TILE = [&](int t, f32x16& Sc, f32x16& Sn, u16x8 (&vc)[4], u16x8 (&vn)[4]) {
    if (t < 31) {
      if (t <= 29)
        asm volatile("s_waitcnt vmcnt(8)" ::: "memory");
      else
        asm volatile("s_waitcnt vmcnt(0)" ::: "memory");
      u16x8 kf[4];
      READ_FRAGS(t + 1, kf, vn);
      asm volatile("s_waitcnt lgkmcnt(0)" ::: "memory");
      __builtin_amdgcn_sched_barrier(0);
      if (t + 3 < 32) STAGE(t + 3, (t + 3) & 1);
#pragma unroll
      for (int r = 0; r < 16; ++r) Sn[r] = 0.f;
      __builtin_amdgcn_s_setprio(1);
#pragma unroll
      for (int ds = 0; ds < 4; ++ds) Sn = mfma32(kf[ds], qf[ds], Sn);
      __builtin_amdgcn_s_setprio(0);
    }
#pragma unroll
    for (int r = 0; r < 16; ++r) {
      float pv = exp2_fast(Sc[r] * C);
      Sc[r] = pv;
      lacc += pv;
    }
    __builtin_amdgcn_s_setprio(1);
#pragma unroll
    for (int m = 0; m < 2; ++m) {
      const int ro = m * 8;
      unsigned w0 = cvtpk_bf16(Sc[ro + 0], Sc[ro + 1]);
      unsigned w2 = cvtpk_bf16(Sc[ro + 4], Sc[ro + 5]);
      unsigned w1 = cvtpk_bf16(Sc[ro + 2], Sc[ro + 3]);
      unsigned w3 = cvtpk_bf16(Sc[ro + 6], Sc[ro + 7]);
      plswap(w0, w2);
      plswap(w1, w3);
      i32x4 aw;
      aw[0] = (int)w0; aw[1] = (int)w1; aw[2] = (int)w2; aw[3] = (int)w3;
      const u16x8 pa = __builtin_bit_cast(u16x8, aw);
#pragma unroll
      for (int d2 = 0; d2 < 2; ++d2) O[d2] = mfma32(pa, vc[m * 2 + d2], O[d2]);
    }
    __builtin_amdgcn_s_setprio(0);
  };

  for (int t = 0; t < 32; t += 2) {
    TILE(t, Sa, Sb, vfA, vfB);
    TILE(t + 1, Sb, Sa, vfB, vfA);
  }

  lacc += __shfl_xor(lacc, 32);
  const float inv = 1.f / lacc;
  const int b = bh >> 4, hh = bh & 15;
#pragma unroll
  for (int r = 0; r < 16; ++r) {
    const int qr = (r & 3) + 8 * (r >> 2) + 4 * h;
    const float invr = __shfl(inv, qr);
    u8* orow = xo + (size_t)(b * 1024 + qrow0 + qr) * 1024 + hh * 64;
    orow[l31] = f2fp8(O[0][r] * invr);
    orow[32 + l31] = f2fp8(O[1][r] * invr);
  }
}

extern "C" void kernel_launch(void* const* d_in, const int* in_sizes, int n_in,
                              void* d_out, int out_size, void* d_ws, size_t ws_size,
                              hipStream_t stream) {
  (void)in_sizes; (void)n_in; (void)out_size; (void)ws_size;
  const float* x      = (const float*)d_in[0];
  const float* norm_g = (const float*)d_in[1];
  const float* norm_b = (const float*)d_in[2];
  const float* W1     = (const float*)d_in[3];
  const float* b1     = (const float*)d_in[4];
  const float* qn_g   = (const float*)d_in[5];
  const float* qn_b   = (const float*)d_in[6];
  const float* kn_g   = (const float*)d_in[7];
  const float* kn_b   = (const float*)d_in[8];
  const float* projW  = (const float*)d_in[9];
  const float* projb  = (const float*)d_in[10];
  const float* mlpW   = (const float*)d_in[11];
  const float* W2     = (const float*)d_in[12];
  const float* b2     = (const float*)d_in[13];
  const float* ls_g   = (const float*)d_in[14];

  char* ws = (char*)d_ws;
  u8*  W1t8 = (u8*)(ws + 0);           // [3840][1024]  3,932,160 (K-tiled)
  u8*  pWt8 = (u8*)(ws + 3932160);     // [1024][1024]  1,048,576 (K-tiled)
  u8*  mWt8 = (u8*)(ws + 4980736);     // [1024][768]     786,432 (K-tiled)
  u8*  W2t8 = (u8*)(ws + 5767168);     // [1024][2048]  2,097,152 (K-tiled)
  u8*  nx8  = (u8*)(ws + 7864320);     // [4096][1024]  4,194,304 (then xo8)
  u16* f1   = (u16*)(ws + 12058624);   // (comb fp8 region)
  u16* qbuf = (u16*)(ws + 43515904);   // [64][1024][64] 8,388,608
  u16* kbuf = (u16*)(ws + 51904512);   // [64][1024][64] 8,388,608
  u16* vtb  = (u16*)(ws + 60293120);   // [64][64][1024] 8,388,608
  u8*  gel8 = (u8*)(ws + 68681728);    // [4096][768]   3,145,728

  k_pre<<<6016, 256, 0, stream>>>(W1, projW, mlpW, W2, W1t8, pWt8, mWt8, W2t8,
                                  x, norm_g, norm_b, nx8);
  k_gemm1<<<960, 256, 0, stream>>>(nx8, W1t8, b1, qn_g, qn_b, kn_g, kn_b,
                                   qbuf, kbuf, vtb, gel8);
  k_flash<<<2048, 64, 0, stream>>>(qbuf, kbuf, vtb, nx8);
  k_gemm_pm<<<dim3(16, 64), 256, 0, stream>>>(nx8, pWt8, gel8, mWt8, (u8*)f1, projb);
  k_gemm_fin<<<dim3(8, 64), 256, 0, stream>>>((u8*)f1, W2t8, (float*)d_out, b2, x,
                                              ls_g);
}